// Round 6
// baseline (484.882 us; speedup 1.0000x reference)
//
#include <hip/hip_runtime.h>
#include <math.h>

// Problem constants (from reference setup_inputs)
#define B_BATCH 2
#define T_SEQ   2048
#define E_DIM   1024
#define H_HEADS 16
#define D_HEAD  64
#define F_DIM   4096
#define M_ROWS  (B_BATCH * T_SEQ)   // 4096

typedef __attribute__((ext_vector_type(8))) short short8;       // bf16x8 MFMA frag
typedef __attribute__((ext_vector_type(4))) float floatx4;      // MFMA acc
typedef __attribute__((ext_vector_type(8))) unsigned short ushortx8;

typedef __attribute__((address_space(1))) const void global_cvoid;
typedef __attribute__((address_space(3))) void lds_void;

__device__ __forceinline__ unsigned short f2bf(float f) {      // RNE f32->bf16
    unsigned u = __float_as_uint(f);
    u += 0x7fffu + ((u >> 16) & 1u);
    return (unsigned short)(u >> 16);
}
__device__ __forceinline__ float bf2f(unsigned short h) {
    return __uint_as_float(((unsigned)h) << 16);
}

// low 32 bits of a generic pointer to __shared__ = LDS byte offset (gfx9+)
__device__ __forceinline__ unsigned lds_lo(const void* p) {
    return (unsigned)(unsigned long long)p;
}

// gelu via A&S 7.1.26 erf: |err| <= 1.5e-7, ~14 VALU ops, no divergence.
__device__ __forceinline__ float gelu_f(float v) {
    const float x = fabsf(v) * 0.70710678118654752f;
    const float t = __builtin_amdgcn_rcpf(__builtin_fmaf(0.3275911f, x, 1.0f));
    float p = __builtin_fmaf(1.061405429f, t, -1.453152027f);
    p = __builtin_fmaf(p, t, 1.421413741f);
    p = __builtin_fmaf(p, t, -0.284496736f);
    p = __builtin_fmaf(p, t, 0.254829592f);
    p *= t;
    const float e = __expf(-x * x);
    float er = __builtin_fmaf(-p, e, 1.0f);          // erf(|x|)
    er = copysignf(er, v);
    return 0.5f * v * (1.0f + er);
}

__device__ __forceinline__ float waveReduceSum(float v) {
#pragma unroll
    for (int off = 32; off > 0; off >>= 1) v += __shfl_xor(v, off, 64);
    return v;
}

// ---------------- LayerNorm row body (shared by prep / ln_kernel) ----------
__device__ __forceinline__ void ln_row(const float* __restrict__ x,
                                       const float* __restrict__ g,
                                       const float* __restrict__ b,
                                       unsigned short* __restrict__ out, int row) {
    const float* xr = x + (size_t)row * E_DIM;
    float4 v = ((const float4*)xr)[threadIdx.x];
    float s  = v.x + v.y + v.z + v.w;
    float sq = v.x * v.x + v.y * v.y + v.z * v.z + v.w * v.w;

    __shared__ float red[8];
    float ws_ = waveReduceSum(s);
    float wq  = waveReduceSum(sq);
    int wid = threadIdx.x >> 6;
    if ((threadIdx.x & 63) == 0) { red[wid] = ws_; red[wid + 4] = wq; }
    __syncthreads();
    float ts = red[0] + red[1] + red[2] + red[3];
    float tq = red[4] + red[5] + red[6] + red[7];
    float mean = ts * (1.0f / E_DIM);
    float var  = tq * (1.0f / E_DIM) - mean * mean;
    float inv  = rsqrtf(var + 1e-5f);

    float4 gv = ((const float4*)g)[threadIdx.x];
    float4 bv = ((const float4*)b)[threadIdx.x];
    ushort4 o;
    o.x = f2bf((v.x - mean) * inv * gv.x + bv.x);
    o.y = f2bf((v.y - mean) * inv * gv.y + bv.y);
    o.z = f2bf((v.z - mean) * inv * gv.z + bv.z);
    o.w = f2bf((v.w - mean) * inv * gv.w + bv.w);
    ((ushort4*)(out + (size_t)row * E_DIM))[threadIdx.x] = o;
}

__global__ __launch_bounds__(256) void ln_kernel(const float* __restrict__ x,
                                                 const float* __restrict__ g,
                                                 const float* __restrict__ b,
                                                 unsigned short* __restrict__ out) {
    ln_row(x, g, b, out, blockIdx.x);
}

// ---------------- fused prep: 4x weight cvt + rope table + LN1 -------------
// block ranges (1024 elems per cvt block):
//  [0,3072) wqkv | [3072,4096) wout | [4096,8192) w1 | [8192,12288) w2
//  [12288,12544) rope tab | [12544,16640) ln1 rows
__global__ __launch_bounds__(256) void prep_kernel(
    const float* __restrict__ in_proj_w, const float* __restrict__ out_proj_w,
    const float* __restrict__ w1, const float* __restrict__ w2,
    const float* __restrict__ x, const float* __restrict__ ln1_g,
    const float* __restrict__ ln1_b,
    unsigned short* __restrict__ wqkv_b, unsigned short* __restrict__ wout_b,
    unsigned short* __restrict__ w1_b, unsigned short* __restrict__ w2_b,
    unsigned short* __restrict__ h_b, float* __restrict__ tab) {
    const int blk = blockIdx.x;
    if (blk < 12288) {
        const float* src; unsigned short* dst; int base;
        if (blk < 3072)      { src = in_proj_w;  dst = wqkv_b; base = blk; }
        else if (blk < 4096) { src = out_proj_w; dst = wout_b; base = blk - 3072; }
        else if (blk < 8192) { src = w1;         dst = w1_b;   base = blk - 4096; }
        else                 { src = w2;         dst = w2_b;   base = blk - 8192; }
        const int i = (base * 256 + threadIdx.x) * 4;
        float4 v = *(const float4*)(src + i);
        ushort4 o;
        o.x = f2bf(v.x); o.y = f2bf(v.y); o.z = f2bf(v.z); o.w = f2bf(v.w);
        *(ushort4*)(dst + i) = o;
    } else if (blk < 12544) {
        const int idx = (blk - 12288) * 256 + threadIdx.x;   // 0..65535
        const int pos = idx >> 5, i = idx & 31;
        const float invf = powf(10000.0f, -(float)i / 32.0f);
        const float ang = (float)pos * invf;
        tab[idx * 2]     = cosf(ang);
        tab[idx * 2 + 1] = sinf(ang);
    } else {
        ln_row(x, ln1_g, ln1_b, h_b, blk - 12544);
    }
}

// ---------------- split-K reduce: out += p0 + p1 + p2 + p3 ------------------
__global__ __launch_bounds__(256) void reduce4_kernel(const float* __restrict__ p,
                                                      float* __restrict__ out, int n) {
    const int i = (blockIdx.x * 256 + threadIdx.x) * 4;
    if (i >= n) return;
    float4 a  = *(const float4*)(out + i);
    float4 b0 = *(const float4*)(p + i);
    float4 b1 = *(const float4*)(p + (size_t)n + i);
    float4 b2 = *(const float4*)(p + 2 * (size_t)n + i);
    float4 b3 = *(const float4*)(p + 3 * (size_t)n + i);
    a.x += b0.x + b1.x + b2.x + b3.x;
    a.y += b0.y + b1.y + b2.y + b3.y;
    a.z += b0.z + b1.z + b2.z + b3.z;
    a.w += b0.w + b1.w + b2.w + b3.w;
    *(float4*)(out + i) = a;
}

// ---------------- 128x128 bf16 MFMA GEMM (kept for out_proj) ----------------
// EPI: 1 = fp32 store acc + R
template <int EPI>
__global__ __launch_bounds__(256) void gemm_bf16(const unsigned short* __restrict__ A,
                                                 const unsigned short* __restrict__ Wt,
                                                 const float* __restrict__ R,
                                                 float* __restrict__ Cf,
                                                 unsigned short* __restrict__ Cb,
                                                 int M, int N, int K) {
    __shared__ unsigned short As[128 * 64];
    __shared__ unsigned short Bs[128 * 64];
    const int tid  = threadIdx.x;
    const int wave = tid >> 6, lane = tid & 63;
    const int wm   = wave >> 1, wn = wave & 1;
    const int quad = lane >> 4, l16 = lane & 15;
    const int m0 = blockIdx.y * 128, n0 = blockIdx.x * 128;
    const int Kc   = K / gridDim.z;
    const int kbeg = blockIdx.z * Kc;

    const int row_rel = lane >> 3;   // 0..7: row within 8-row DMA chunk
    const int ch      = lane & 7;    // phys 16B chunk within row

    const floatx4 z = {0.0f, 0.0f, 0.0f, 0.0f};
    floatx4 acc[4][4];
#pragma unroll
    for (int i = 0; i < 4; ++i)
#pragma unroll
        for (int j = 0; j < 4; ++j) acc[i][j] = z;

    for (int k0 = kbeg; k0 < kbeg + Kc; k0 += 64) {
        __syncthreads();
#pragma unroll
        for (int i = 0; i < 4; ++i) {
            const int chunk = wave * 4 + i;          // 0..15 (8 rows each)
            const int grow  = chunk * 8 + row_rel;   // tile row 0..127
            const int lch   = ch ^ (grow & 7);       // swizzled source chunk
            const unsigned short* ga = A  + (size_t)(m0 + grow) * K + k0 + lch * 8;
            const unsigned short* gb = Wt + (size_t)(n0 + grow) * K + k0 + lch * 8;
            __builtin_amdgcn_global_load_lds((global_cvoid*)ga,
                                             (lds_void*)(As + chunk * 512), 16, 0, 0);
            __builtin_amdgcn_global_load_lds((global_cvoid*)gb,
                                             (lds_void*)(Bs + chunk * 512), 16, 0, 0);
        }
        __syncthreads();

#pragma unroll
        for (int ks = 0; ks < 2; ++ks) {
            short8 af[4], bfr[4];
#pragma unroll
            for (int mt = 0; mt < 4; ++mt) {
                const int r = wm * 64 + mt * 16 + l16;
                const int p = (ks * 4 + quad) ^ (r & 7);
                af[mt] = *(const short8*)(As + r * 64 + p * 8);
            }
#pragma unroll
            for (int nt = 0; nt < 4; ++nt) {
                const int r = wn * 64 + nt * 16 + l16;
                const int p = (ks * 4 + quad) ^ (r & 7);
                bfr[nt] = *(const short8*)(Bs + r * 64 + p * 8);
            }
#pragma unroll
            for (int mt = 0; mt < 4; ++mt)
#pragma unroll
                for (int nt = 0; nt < 4; ++nt)
                    acc[mt][nt] = __builtin_amdgcn_mfma_f32_16x16x32_bf16(
                        af[mt], bfr[nt], acc[mt][nt], 0, 0, 0);
        }
    }

    // Epilogue. C/D layout: col = lane&15, row = quad*4 + reg  [m89-verified]
#pragma unroll
    for (int mt = 0; mt < 4; ++mt) {
        const int rb = m0 + wm * 64 + mt * 16 + quad * 4;
#pragma unroll
        for (int nt = 0; nt < 4; ++nt) {
            const int col = n0 + wn * 64 + nt * 16 + l16;
#pragma unroll
            for (int r = 0; r < 4; ++r) {
                const size_t idx = (size_t)(rb + r) * N + col;
                const float v = acc[mt][nt][r];
                if (EPI == 1) {
                    Cf[idx] = v + R[idx];
                } else {
                    Cf[idx] = v;
                }
            }
        }
    }
}

// ---------------- 256x256 bf16 MFMA GEMM, BK=64, double-buffered ------------
// 512 threads, 8 waves (2M x 4N), per-wave output 128x64.
// LDS: 2 x (A 32KB + B 32KB) = 128 KB.
//
// R4 post-mortem: wall per barrier-group was ~3400 cyc regardless of BK
// (fixed cost: 8-wave LDS queue drain + barrier skew + issue overhead), so
// BK=32 amortized it over only 32 MFMA. This version doubles work per group
// (64 MFMA) at the same fixed cost. vmcnt(0) at step end is now ~free: the
// staged tile was issued a full step (~2000 cyc) before the wait (> HBM
// latency). k1 frag reads are issued BEFORE the k0 MFMA cluster so their LDS
// drain hides under it. All ds_reads are inline asm (invisible to
// SIInsertWaitcnts — R3 lesson) with lgkmcnt(0)+sched_barrier (rule #18).
// Row = 128B -> full 3-bit XOR swizzle (same mapping as 128^2 kernel).
// NT = K/(gridDim.z*64) must be even >= 4 (all call sites: 16).
// EPI: 2 = bf16 store gelu(acc), 4 = bf16 store, 5 = fp32 partial (z-sliced)
template <int EPI>
__global__ __launch_bounds__(512, 2) void gemm256_bf16(const unsigned short* __restrict__ A,
                                                       const unsigned short* __restrict__ Wt,
                                                       float* __restrict__ Cf,
                                                       unsigned short* __restrict__ Cb,
                                                       int M, int N, int K) {
    __shared__ __align__(16) unsigned short Ls[2 * 32768];   // 128 KB

    const int tid  = threadIdx.x;
    const int wave = tid >> 6, lane = tid & 63;
    const int wm   = wave >> 2, wn = wave & 3;
    const int quad = lane >> 4, l16 = lane & 15;

    // bijective XCD swizzle over the (x,y) grid (nwg % 8 == 0 at all call sites)
    int bid = blockIdx.y * gridDim.x + blockIdx.x;
    const int cpx = (gridDim.x * gridDim.y) >> 3;
    bid = (bid & 7) * cpx + (bid >> 3);
    const int bx = bid % gridDim.x, by = bid / gridDim.x;
    const int m0 = by * 256, n0 = bx * 256;

    const int Kc   = K / gridDim.z;
    const int kbeg = blockIdx.z * Kc;
    const int NT   = Kc >> 6;                 // K-steps of 64 (16 at call sites)

    const int rr8 = lane >> 3;                // 0..7: row within 8-row DMA chunk
    const int ch8 = lane & 7;                 // phys 16B chunk within 128B row

    const floatx4 z = {0.0f, 0.0f, 0.0f, 0.0f};
    floatx4 acc[8][4];
#pragma unroll
    for (int i = 0; i < 8; ++i)
#pragma unroll
        for (int j = 0; j < 4; ++j) acc[i][j] = z;

    // stage K-tile t (256x64) into buffer bi: 4x A + 4x B DMA per thread.
    // logical chunk c of row r stored at phys c ^ (r&7) via pre-swizzled
    // source (LDS dest linear — rule #21); same mapping as 128^2 kernel.
    auto STAGE = [&](int t, int bi) {
        const int k0 = kbeg + t * 64;
#pragma unroll
        for (int i = 0; i < 4; ++i) {
            const int ca   = wave * 4 + i;          // chunk 0..31 (8 rows each)
            const int grow = ca * 8 + rr8;          // tile row 0..255
            const int lch  = ch8 ^ (grow & 7);      // swizzled source chunk
            const unsigned short* ga = A  + (size_t)(m0 + grow) * K + k0 + lch * 8;
            const unsigned short* gb = Wt + (size_t)(n0 + grow) * K + k0 + lch * 8;
            unsigned short* la = Ls + bi * 32768 + ca * 512;
            __builtin_amdgcn_global_load_lds((global_cvoid*)ga, (lds_void*)la, 16, 0, 0);
            __builtin_amdgcn_global_load_lds((global_cvoid*)gb,
                                             (lds_void*)(la + 16384), 16, 0, 0);
        }
    };

    // per-thread LDS byte addresses (buffer 0): row*128 + phys_chunk*16,
    // phys = (ks*4+quad) ^ (r&7); r&7 == l16&7 for all frags.
    const unsigned e3  = (unsigned)(l16 & 7);
    const unsigned rA  = (unsigned)(wm * 128 + l16) * 128u;
    const unsigned rB  = (unsigned)(wn * 64 + l16) * 128u;
    const unsigned aA0 = lds_lo(Ls) + rA + ((unsigned)quad ^ e3) * 16u;
    const unsigned aA1 = lds_lo(Ls) + rA + ((unsigned)(4 + quad) ^ e3) * 16u;
    const unsigned aB0 = lds_lo(Ls) + 32768u + rB + ((unsigned)quad ^ e3) * 16u;
    const unsigned aB1 = lds_lo(Ls) + 32768u + rB + ((unsigned)(4 + quad) ^ e3) * 16u;

#define GSTEP(T, C, DOPF, DOBAR)                                               \
    do {                                                                       \
        short8 a0[8], b0[4], a1[8], b1[4];                                     \
        const unsigned uA0 = aA0 + (C) * 65536u;                               \
        const unsigned uB0 = aB0 + (C) * 65536u;                               \
        const unsigned uA1 = aA1 + (C) * 65536u;                               \
        const unsigned uB1 = aB1 + (C) * 65536u;                               \
        _Pragma("unroll")                                                      \
        for (int mt = 0; mt < 8; ++mt)                                         \
            asm volatile("ds_read_b128 %0, %1"                                 \
                         : "=v"(a0[mt]) : "v"(uA0 + mt * 2048u));              \
        _Pragma("unroll")                                                      \
        for (int nt = 0; nt < 4; ++nt)                                         \
            asm volatile("ds_read_b128 %0, %1"                                 \
                         : "=v"(b0[nt]) : "v"(uB0 + nt * 2048u));              \
        if (DOPF) STAGE((T) + 1, (C) ^ 1);                                     \
        asm volatile("s_waitcnt lgkmcnt(0)" ::: "memory");                     \
        __builtin_amdgcn_sched_barrier(0);                                     \
        _Pragma("unroll")                                                      \
        for (int mt = 0; mt < 8; ++mt)                                         \
            asm volatile("ds_read_b128 %0, %1"                                 \
                         : "=v"(a1[mt]) : "v"(uA1 + mt * 2048u));              \
        _Pragma("unroll")                                                      \
        for (int nt = 0; nt < 4; ++nt)                                         \
            asm volatile("ds_read_b128 %0, %1"                                 \
                         : "=v"(b1[nt]) : "v"(uB1 + nt * 2048u));              \
        __builtin_amdgcn_sched_barrier(0);                                     \
        __builtin_amdgcn_s_setprio(1);                                         \
        _Pragma("unroll")                                                      \
        for (int mt = 0; mt < 8; ++mt)                                         \
            _Pragma("unroll")                                                  \
            for (int nt = 0; nt < 4; ++nt)                                     \
                acc[mt][nt] = __builtin_amdgcn_mfma_f32_16x16x32_bf16(         \
                    a0[mt], b0[nt], acc[mt][nt], 0, 0, 0);                     \
        __builtin_amdgcn_s_setprio(0);                                         \
        asm volatile("s_waitcnt lgkmcnt(0)" ::: "memory");                     \
        __builtin_amdgcn_sched_barrier(0);                                     \
        __builtin_amdgcn_s_setprio(1);                                         \
        _Pragma("unroll")                                                      \
        for (int mt = 0; mt < 8; ++mt)                                         \
            _Pragma("unroll")                                                  \
            for (int nt = 0; nt < 4; ++nt)                                     \
                acc[mt][nt] = __builtin_amdgcn_mfma_f32_16x16x32_bf16(         \
                    a1[mt], b1[nt], acc[mt][nt], 0, 0, 0);                     \
        __builtin_amdgcn_s_setprio(0);                                         \
        if (DOBAR) {                                                           \
            asm volatile("s_waitcnt vmcnt(0)" ::: "memory");                   \
            __builtin_amdgcn_s_barrier();                                      \
            __builtin_amdgcn_sched_barrier(0);                                 \
        }                                                                      \
    } while (0)

    // prologue: tile 0 into buf 0
    STAGE(0, 0);
    asm volatile("s_waitcnt vmcnt(0)" ::: "memory");
    __builtin_amdgcn_s_barrier();
    __builtin_amdgcn_sched_barrier(0);

    int t = 0;
    for (; t < NT - 2; t += 2) {
        GSTEP(t + 0, 0, true, true);
        GSTEP(t + 1, 1, true, true);
    }
    GSTEP(t + 0, 0, true, true);     // t = NT-2, stages NT-1
    GSTEP(t + 1, 1, false, false);   // t = NT-1, last: no stage/wait/barrier
#undef GSTEP

    // Epilogue. C/D layout: col = lane&15, row = quad*4 + reg  [m89-verified]
    const size_t zoff = (size_t)blockIdx.z * M * N;
#pragma unroll
    for (int mt = 0; mt < 8; ++mt) {
        const int rb = m0 + wm * 128 + mt * 16 + quad * 4;
#pragma unroll
        for (int nt = 0; nt < 4; ++nt) {
            const int col = n0 + wn * 64 + nt * 16 + l16;
#pragma unroll
            for (int r = 0; r < 4; ++r) {
                const size_t idx = (size_t)(rb + r) * N + col;
                const float v = acc[mt][nt][r];
                if (EPI == 2) {
                    Cb[idx] = f2bf(gelu_f(v));
                } else if (EPI == 4) {
                    Cb[idx] = f2bf(v);
                } else {
                    Cf[zoff + idx] = v;   // split-K partial, coalesced
                }
            }
        }
    }
}

// ---------------- V transpose: proj v-part -> vt[(bh*64+d)][T] bf16 --------
__global__ __launch_bounds__(256) void vtrans_kernel(const unsigned short* __restrict__ proj,
                                                     unsigned short* __restrict__ vt) {
    __shared__ unsigned short L[64 * 72];
    const int bh = blockIdx.y, b = bh >> 4, h = bh & 15;
    const int st = blockIdx.x * 64;
    const int tid = threadIdx.x;
    {
        const int srel = tid >> 2, d16 = (tid & 3) * 16;
        const unsigned short* src =
            proj + (size_t)(b * T_SEQ + st + srel) * (3 * E_DIM) + 2 * E_DIM + h * 64 + d16;
        *(short8*)(L + srel * 72 + d16)     = *(const short8*)(src);
        *(short8*)(L + srel * 72 + d16 + 8) = *(const short8*)(src + 8);
    }
    __syncthreads();
    {
        const int d = tid >> 2, s16 = (tid & 3) * 16;
        short8 o0, o1;
#pragma unroll
        for (int j = 0; j < 8; ++j) {
            o0[j] = (short)L[(s16 + j) * 72 + d];
            o1[j] = (short)L[(s16 + 8 + j) * 72 + d];
        }
        unsigned short* dst = vt + (size_t)(bh * 64 + d) * T_SEQ + st + s16;
        *(short8*)dst       = o0;
        *(short8*)(dst + 8) = o1;
    }
}

// ---------------- Flash attention w/ fused RoPE, MFMA -----------------------
__device__ __forceinline__ void rope16(ushortx8 x0, ushortx8 x1, const float* tp,
                                       short8& y0, short8& y1) {
#pragma unroll
    for (int j = 0; j < 4; ++j) {
        const float c = tp[2 * j], s = tp[2 * j + 1];
        const float xr = bf2f(x0[2 * j]), xi = bf2f(x0[2 * j + 1]);
        y0[2 * j]     = (short)f2bf(xr * c - xi * s);
        y0[2 * j + 1] = (short)f2bf(xr * s + xi * c);
    }
#pragma unroll
    for (int j = 0; j < 4; ++j) {
        const float c = tp[8 + 2 * j], s = tp[8 + 2 * j + 1];
        const float xr = bf2f(x1[2 * j]), xi = bf2f(x1[2 * j + 1]);
        y1[2 * j]     = (short)f2bf(xr * c - xi * s);
        y1[2 * j + 1] = (short)f2bf(xr * s + xi * c);
    }
}

__global__ __launch_bounds__(256) void attn_kernel(const unsigned short* __restrict__ proj,
                                                   const unsigned short* __restrict__ vt,
                                                   const float* __restrict__ tab,
                                                   const int* __restrict__ ctxp,
                                                   unsigned short* __restrict__ o) {
    __shared__ unsigned short Qs[64 * 64];
    __shared__ unsigned short Ks[64 * 64];
    __shared__ unsigned short Vs[64 * 64];
    __shared__ unsigned short Ps[4][16 * 64];

    const int ctx = ctxp[0];
    const int tid = threadIdx.x;
    const int wave = tid >> 6, lane = tid & 63;
    const int quad = lane >> 4, l16 = lane & 15;
    const int bh = blockIdx.y, b = bh >> 4, h = bh & 15;
    const int t0 = blockIdx.x * 64;

    // ---- stage Q with RoPE (rows swizzled: chunk c at phys c^(row&7)) ----
    {
        const int r = tid >> 2, d16 = (tid & 3) * 16;
        const int pos = t0 + r;
        const unsigned short* src =
            proj + (size_t)(b * T_SEQ + pos) * (3 * E_DIM) + h * 64 + d16;
        ushortx8 x0 = *(const ushortx8*)src;
        ushortx8 x1 = *(const ushortx8*)(src + 8);
        const float* tp = tab + ((size_t)pos * 32 + (d16 >> 1)) * 2;
        short8 y0, y1;
        rope16(x0, x1, tp, y0, y1);
        const int c0 = (tid & 3) * 2;
        *(short8*)(Qs + r * 64 + ((c0)     ^ (r & 7)) * 8) = y0;
        *(short8*)(Qs + r * 64 + ((c0 + 1) ^ (r & 7)) * 8) = y1;
    }

    int first = t0 - (ctx - 1);
    if (first < 0) first = 0;
    const int first_base = first & ~63;

    float m[4] = {-1e30f, -1e30f, -1e30f, -1e30f};
    float l[4] = {0.0f, 0.0f, 0.0f, 0.0f};
    const floatx4 z = {0.0f, 0.0f, 0.0f, 0.0f};
    floatx4 accO[4] = {z, z, z, z};

    const int q_row0 = t0 + wave * 16 + quad * 4;   // abs query of reg r=0

    for (int s_base = first_base; s_base <= t0; s_base += 64) {
        __syncthreads();
        // ---- stage K with RoPE ----
        {
            const int r = tid >> 2, d16 = (tid & 3) * 16;
            const int pos = s_base + r;
            const unsigned short* src =
                proj + (size_t)(b * T_SEQ + pos) * (3 * E_DIM) + E_DIM + h * 64 + d16;
            ushortx8 x0 = *(const ushortx8*)src;
            ushortx8 x1 = *(const ushortx8*)(src + 8);
            const float* tp = tab + ((size_t)pos * 32 + (d16 >> 1)) * 2;
            short8 y0, y1;
            rope16(x0, x1, tp, y0, y1);
            const int c0 = (tid & 3) * 2;
            *(short8*)(Ks + r * 64 + ((c0)     ^ (r & 7)) * 8) = y0;
            *(short8*)(Ks + r * 64 + ((c0 + 1) ^ (r & 7)) * 8) = y1;
        }
        // ---- stage V^T tile via DMA (row d, cols s_base..+63, swizzled) ----
#pragma unroll
        for (int i = 0; i < 2; ++i) {
            const int chunk = (wave * 2 + i) * 64 + lane;   // 0..511
            const int d = chunk >> 3, c = chunk & 7;
            const unsigned short* gsrc =
                vt + (size_t)(bh * 64 + d) * T_SEQ + s_base + ((c ^ (d & 7)) * 8);
            __builtin_amdgcn_global_load_lds((global_cvoid*)gsrc,
                                             (lds_void*)(Vs + (wave * 2 + i) * 512),
                                             16, 0, 0);
        }
        __syncthreads();

        // ---- S = Q K^T (8 MFMA) ----
        floatx4 accS[4] = {z, z, z, z};
#pragma unroll
        for (int ks = 0; ks < 2; ++ks) {
            const int qrow = wave * 16 + l16;
            short8 aq = *(const short8*)(Qs + qrow * 64 + (((ks * 4 + quad) ^ (qrow & 7)) * 8));
#pragma unroll
            for (int nt = 0; nt < 4; ++nt) {
                const int kro = nt * 16 + l16;
                short8 bk = *(const short8*)(Ks + kro * 64 + (((ks * 4 + quad) ^ (kro & 7)) * 8));
                accS[nt] = __builtin_amdgcn_mfma_f32_16x16x32_bf16(aq, bk, accS[nt], 0, 0, 0);
            }
        }

        // ---- mask + online softmax (per q-row r = quad*4+reg) ----
        float p[4][4];      // [nt][r]
        float alpha[4];
#pragma unroll
        for (int r = 0; r < 4; ++r) {
            const int qa = q_row0 + r;
            float sv[4];
            float vmax = -1e30f;
#pragma unroll
            for (int nt = 0; nt < 4; ++nt) {
                const int sa = s_base + nt * 16 + l16;
                const int dd = qa - sa;
                const bool ok = (unsigned)dd < (unsigned)ctx;
                const float s = ok ? accS[nt][r] * 0.125f : -1e30f;
                sv[nt] = s;
                vmax = fmaxf(vmax, s);
            }
            vmax = fmaxf(vmax, __shfl_xor(vmax, 1));
            vmax = fmaxf(vmax, __shfl_xor(vmax, 2));
            vmax = fmaxf(vmax, __shfl_xor(vmax, 4));
            vmax = fmaxf(vmax, __shfl_xor(vmax, 8));
            const float mn = fmaxf(m[r], vmax);
            alpha[r] = __expf(m[r] - mn);
            float ps = 0.0f;
#pragma unroll
            for (int nt = 0; nt < 4; ++nt) {
                const float pe = (sv[nt] > -0.5e30f) ? __expf(sv[nt] - mn) : 0.0f;
                p[nt][r] = pe;
                ps += pe;
            }
            ps += __shfl_xor(ps, 1);
            ps += __shfl_xor(ps, 2);
            ps += __shfl_xor(ps, 4);
            ps += __shfl_xor(ps, 8);
            l[r] = l[r] * alpha[r] + ps;
            m[r] = mn;
        }

        // ---- write P to LDS (C-layout -> A-layout), rescale O ----
#pragma unroll
        for (int nt = 0; nt < 4; ++nt) {
#pragma unroll
            for (int r = 0; r < 4; ++r) {
                const int row = quad * 4 + r;
                const int col = nt * 16 + l16;
                Ps[wave][row * 64 + (((col >> 3) ^ (row & 7)) * 8) + (col & 7)] =
                    f2bf(p[nt][r]);
            }
        }
#pragma unroll
        for (int nt = 0; nt < 4; ++nt)
#pragma unroll
            for (int r = 0; r < 4; ++r) accO[nt][r] *= alpha[r];

        // ---- O += P V (8 MFMA) ----
#pragma unroll
        for (int ks = 0; ks < 2; ++ks) {
            short8 ap = *(const short8*)(&Ps[wave][l16 * 64 + (((ks * 4 + quad) ^ (l16 & 7)) * 8)]);
#pragma unroll
            for (int nt = 0; nt < 4; ++nt) {
                const int dr = nt * 16 + l16;
                short8 bv = *(const short8*)(Vs + dr * 64 + (((ks * 4 + quad) ^ (dr & 7)) * 8));
                accO[nt] = __builtin_amdgcn_mfma_f32_16x16x32_bf16(ap, bv, accO[nt], 0, 0, 0);
            }
        }
    }

    // ---- epilogue: normalize, store bf16 to (B,T,E) ----
    float inv[4];
#pragma unroll
    for (int r = 0; r < 4; ++r) inv[r] = 1.0f / l[r];
#pragma unroll
    for (int nt = 0; nt < 4; ++nt) {
#pragma unroll
        for (int r = 0; r < 4; ++r) {
            const int t = q_row0 + r;
            o[(size_t)(b * T_SEQ + t) * E_DIM + h * 64 + nt * 16 + l16] =
                f2bf(accO[nt][r] * inv[r]);
        }
    }
}

// ---------------------------------------------------------------------------
extern "C" void kernel_launch(void* const* d_in, const int* in_sizes, int n_in,
                              void* d_out, int out_size, void* d_ws, size_t ws_size,
                              hipStream_t stream) {
    const float* x          = (const float*)d_in[0];
    const float* in_proj_w  = (const float*)d_in[1];
    const float* out_proj_w = (const float*)d_in[2];
    const float* ln1_g      = (const float*)d_in[3];
    const float* ln1_b      = (const float*)d_in[4];
    const float* ln2_g      = (const float*)d_in[5];
    const float* ln2_b      = (const float*)d_in[6];
    const float* w1         = (const float*)d_in[7];
    const float* w2         = (const float*)d_in[8];
    const int*   ctx        = (const int*)d_in[9];
    float* out = (float*)d_out;
    float* ws  = (float*)d_ws;

    // Workspace layout (byte offsets); split-K partials (bytes 0..64M) overlay
    // regions that are ALL dead during the MLP2 GEMM:
    //   0.. 6M  wqkv_b | 6..8M wout_b | 8..16M w1_b | 16..24M h_b
    //  24..32M  obuf_b | 32..56M proj_b | 56..64M vt_b
    //  64..96M  mid_b  | 96..104M w2_b | 104..104.5M tab
    const size_t MEG = 1024u * 1024u;
    unsigned short* u = (unsigned short*)ws;
    unsigned short* wqkv_b = u;                 // bytes   0..6
    unsigned short* wout_b = u + 3 * MEG;       // bytes   6..8
    unsigned short* w1_b   = u + 4 * MEG;       // bytes   8..16
    unsigned short* h_b    = u + 8 * MEG;       // bytes  16..24
    unsigned short* obuf_b = u + 12 * MEG;      // bytes  24..32
    unsigned short* proj_b = u + 16 * MEG;      // bytes  32..56
    unsigned short* vt_b   = u + 28 * MEG;      // bytes  56..64
    unsigned short* mid_b  = u + 32 * MEG;      // bytes  64..96
    unsigned short* w2_b   = u + 48 * MEG;      // bytes  96..104
    float* tab  = ws + 26 * MEG;                // bytes 104..104.5
    float* part = ws;                           // 4 slices x 16 MB, bytes 0..64

    // 0+1. fused: weights->bf16, rope table, h1 = LN1(x)  (was 6 launches)
    prep_kernel<<<16640, 256, 0, stream>>>(in_proj_w, out_proj_w, w1, w2,
                                           x, ln1_g, ln1_b,
                                           wqkv_b, wout_b, w1_b, w2_b, h_b, tab);
    // 2. proj = h1 @ in_proj_w^T -> bf16   (256², 192 blocks)
    gemm256_bf16<4><<<dim3(3 * E_DIM / 256, M_ROWS / 256), 512, 0, stream>>>(
        h_b, wqkv_b, nullptr, proj_b, M_ROWS, 3 * E_DIM, E_DIM);
    // 3. V^T
    vtrans_kernel<<<dim3(T_SEQ / 64, B_BATCH * H_HEADS), 256, 0, stream>>>(proj_b, vt_b);
    // 4. flash attention (fused RoPE) -> obuf bf16 (B,T,E)
    attn_kernel<<<dim3(T_SEQ / 64, B_BATCH * H_HEADS), 256, 0, stream>>>(
        proj_b, vt_b, tab, ctx, obuf_b);
    // 5. out = x + obuf @ out_proj_w^T (fused residual store; 128² kernel)
    gemm_bf16<1><<<dim3(E_DIM / 128, M_ROWS / 128), 256, 0, stream>>>(
        obuf_b, wout_b, x, out, nullptr, M_ROWS, E_DIM, E_DIM);
    // 6. h2 = LN2(out) -> bf16
    ln_kernel<<<M_ROWS, 256, 0, stream>>>(out, ln2_g, ln2_b, h_b);
    // 7. mid = gelu(h2 @ w1^T) -> bf16   (256², 256 blocks)
    gemm256_bf16<2><<<dim3(F_DIM / 256, M_ROWS / 256), 512, 0, stream>>>(
        h_b, w1_b, nullptr, mid_b, M_ROWS, F_DIM, E_DIM);
    // 8. part[z] = mid @ w2^T (split-K=4, Kc=1024, 256 blocks), out += Σ part
    gemm256_bf16<5><<<dim3(E_DIM / 256, M_ROWS / 256, 4), 512, 0, stream>>>(
        mid_b, w2_b, part, nullptr, M_ROWS, E_DIM, F_DIM);
    reduce4_kernel<<<M_ROWS * E_DIM / 1024, 256, 0, stream>>>(
        part, out, M_ROWS * E_DIM);
}

// Round 8
// 319.513 us; speedup vs baseline: 1.5176x; 1.5176x over previous
//
#include <hip/hip_runtime.h>
#include <math.h>

// Problem constants (from reference setup_inputs)
#define B_BATCH 2
#define T_SEQ   2048
#define E_DIM   1024
#define H_HEADS 16
#define D_HEAD  64
#define F_DIM   4096
#define M_ROWS  (B_BATCH * T_SEQ)   // 4096

typedef __attribute__((ext_vector_type(8))) short short8;       // bf16x8 MFMA frag
typedef __attribute__((ext_vector_type(4))) float floatx4;      // MFMA acc
typedef __attribute__((ext_vector_type(8))) unsigned short ushortx8;

typedef __attribute__((address_space(1))) const void global_cvoid;
typedef __attribute__((address_space(3))) void lds_void;

__device__ __forceinline__ unsigned short f2bf(float f) {      // RNE f32->bf16
    unsigned u = __float_as_uint(f);
    u += 0x7fffu + ((u >> 16) & 1u);
    return (unsigned short)(u >> 16);
}
__device__ __forceinline__ float bf2f(unsigned short h) {
    return __uint_as_float(((unsigned)h) << 16);
}

// low 32 bits of a generic pointer to __shared__ = LDS byte offset (gfx9+)
__device__ __forceinline__ unsigned lds_lo(const void* p) {
    return (unsigned)(unsigned long long)p;
}

// gelu via A&S 7.1.26 erf: |err| <= 1.5e-7, ~14 VALU ops, no divergence.
__device__ __forceinline__ float gelu_f(float v) {
    const float x = fabsf(v) * 0.70710678118654752f;
    const float t = __builtin_amdgcn_rcpf(__builtin_fmaf(0.3275911f, x, 1.0f));
    float p = __builtin_fmaf(1.061405429f, t, -1.453152027f);
    p = __builtin_fmaf(p, t, 1.421413741f);
    p = __builtin_fmaf(p, t, -0.284496736f);
    p = __builtin_fmaf(p, t, 0.254829592f);
    p *= t;
    const float e = __expf(-x * x);
    float er = __builtin_fmaf(-p, e, 1.0f);          // erf(|x|)
    er = copysignf(er, v);
    return 0.5f * v * (1.0f + er);
}

__device__ __forceinline__ float waveReduceSum(float v) {
#pragma unroll
    for (int off = 32; off > 0; off >>= 1) v += __shfl_xor(v, off, 64);
    return v;
}

// ---------------- LayerNorm row body (shared by prep / ln_kernel) ----------
__device__ __forceinline__ void ln_row(const float* __restrict__ x,
                                       const float* __restrict__ g,
                                       const float* __restrict__ b,
                                       unsigned short* __restrict__ out, int row) {
    const float* xr = x + (size_t)row * E_DIM;
    float4 v = ((const float4*)xr)[threadIdx.x];
    float s  = v.x + v.y + v.z + v.w;
    float sq = v.x * v.x + v.y * v.y + v.z * v.z + v.w * v.w;

    __shared__ float red[8];
    float ws_ = waveReduceSum(s);
    float wq  = waveReduceSum(sq);
    int wid = threadIdx.x >> 6;
    if ((threadIdx.x & 63) == 0) { red[wid] = ws_; red[wid + 4] = wq; }
    __syncthreads();
    float ts = red[0] + red[1] + red[2] + red[3];
    float tq = red[4] + red[5] + red[6] + red[7];
    float mean = ts * (1.0f / E_DIM);
    float var  = tq * (1.0f / E_DIM) - mean * mean;
    float inv  = rsqrtf(var + 1e-5f);

    float4 gv = ((const float4*)g)[threadIdx.x];
    float4 bv = ((const float4*)b)[threadIdx.x];
    ushort4 o;
    o.x = f2bf((v.x - mean) * inv * gv.x + bv.x);
    o.y = f2bf((v.y - mean) * inv * gv.y + bv.y);
    o.z = f2bf((v.z - mean) * inv * gv.z + bv.z);
    o.w = f2bf((v.w - mean) * inv * gv.w + bv.w);
    ((ushort4*)(out + (size_t)row * E_DIM))[threadIdx.x] = o;
}

__global__ __launch_bounds__(256) void ln_kernel(const float* __restrict__ x,
                                                 const float* __restrict__ g,
                                                 const float* __restrict__ b,
                                                 unsigned short* __restrict__ out) {
    ln_row(x, g, b, out, blockIdx.x);
}

// ---------------- fused prep: 4x weight cvt + rope table + LN1 -------------
// block ranges (1024 elems per cvt block):
//  [0,3072) wqkv | [3072,4096) wout | [4096,8192) w1 | [8192,12288) w2
//  [12288,12544) rope tab | [12544,16640) ln1 rows
__global__ __launch_bounds__(256) void prep_kernel(
    const float* __restrict__ in_proj_w, const float* __restrict__ out_proj_w,
    const float* __restrict__ w1, const float* __restrict__ w2,
    const float* __restrict__ x, const float* __restrict__ ln1_g,
    const float* __restrict__ ln1_b,
    unsigned short* __restrict__ wqkv_b, unsigned short* __restrict__ wout_b,
    unsigned short* __restrict__ w1_b, unsigned short* __restrict__ w2_b,
    unsigned short* __restrict__ h_b, float* __restrict__ tab) {
    const int blk = blockIdx.x;
    if (blk < 12288) {
        const float* src; unsigned short* dst; int base;
        if (blk < 3072)      { src = in_proj_w;  dst = wqkv_b; base = blk; }
        else if (blk < 4096) { src = out_proj_w; dst = wout_b; base = blk - 3072; }
        else if (blk < 8192) { src = w1;         dst = w1_b;   base = blk - 4096; }
        else                 { src = w2;         dst = w2_b;   base = blk - 8192; }
        const int i = (base * 256 + threadIdx.x) * 4;
        float4 v = *(const float4*)(src + i);
        ushort4 o;
        o.x = f2bf(v.x); o.y = f2bf(v.y); o.z = f2bf(v.z); o.w = f2bf(v.w);
        *(ushort4*)(dst + i) = o;
    } else if (blk < 12544) {
        const int idx = (blk - 12288) * 256 + threadIdx.x;   // 0..65535
        const int pos = idx >> 5, i = idx & 31;
        const float invf = powf(10000.0f, -(float)i / 32.0f);
        const float ang = (float)pos * invf;
        tab[idx * 2]     = cosf(ang);
        tab[idx * 2 + 1] = sinf(ang);
    } else {
        ln_row(x, ln1_g, ln1_b, h_b, blk - 12544);
    }
}

// ---------------- split-K reduce: out += p0 + p1 + p2 + p3 ------------------
__global__ __launch_bounds__(256) void reduce4_kernel(const float* __restrict__ p,
                                                      float* __restrict__ out, int n) {
    const int i = (blockIdx.x * 256 + threadIdx.x) * 4;
    if (i >= n) return;
    float4 a  = *(const float4*)(out + i);
    float4 b0 = *(const float4*)(p + i);
    float4 b1 = *(const float4*)(p + (size_t)n + i);
    float4 b2 = *(const float4*)(p + 2 * (size_t)n + i);
    float4 b3 = *(const float4*)(p + 3 * (size_t)n + i);
    a.x += b0.x + b1.x + b2.x + b3.x;
    a.y += b0.y + b1.y + b2.y + b3.y;
    a.z += b0.z + b1.z + b2.z + b3.z;
    a.w += b0.w + b1.w + b2.w + b3.w;
    *(float4*)(out + i) = a;
}

// ---------------- 128x128 bf16 MFMA GEMM (out_proj; m97 structure) ----------
// EPI: 1 = fp32 store acc + R
template <int EPI>
__global__ __launch_bounds__(256) void gemm_bf16(const unsigned short* __restrict__ A,
                                                 const unsigned short* __restrict__ Wt,
                                                 const float* __restrict__ R,
                                                 float* __restrict__ Cf,
                                                 unsigned short* __restrict__ Cb,
                                                 int M, int N, int K) {
    __shared__ unsigned short As[128 * 64];
    __shared__ unsigned short Bs[128 * 64];
    const int tid  = threadIdx.x;
    const int wave = tid >> 6, lane = tid & 63;
    const int wm   = wave >> 1, wn = wave & 1;
    const int quad = lane >> 4, l16 = lane & 15;
    const int m0 = blockIdx.y * 128, n0 = blockIdx.x * 128;
    const int Kc   = K / gridDim.z;
    const int kbeg = blockIdx.z * Kc;

    const int row_rel = lane >> 3;   // 0..7: row within 8-row DMA chunk
    const int ch      = lane & 7;    // phys 16B chunk within row

    const floatx4 z = {0.0f, 0.0f, 0.0f, 0.0f};
    floatx4 acc[4][4];
#pragma unroll
    for (int i = 0; i < 4; ++i)
#pragma unroll
        for (int j = 0; j < 4; ++j) acc[i][j] = z;

    for (int k0 = kbeg; k0 < kbeg + Kc; k0 += 64) {
        __syncthreads();
#pragma unroll
        for (int i = 0; i < 4; ++i) {
            const int chunk = wave * 4 + i;          // 0..15 (8 rows each)
            const int grow  = chunk * 8 + row_rel;   // tile row 0..127
            const int lch   = ch ^ (grow & 7);       // swizzled source chunk
            const unsigned short* ga = A  + (size_t)(m0 + grow) * K + k0 + lch * 8;
            const unsigned short* gb = Wt + (size_t)(n0 + grow) * K + k0 + lch * 8;
            __builtin_amdgcn_global_load_lds((global_cvoid*)ga,
                                             (lds_void*)(As + chunk * 512), 16, 0, 0);
            __builtin_amdgcn_global_load_lds((global_cvoid*)gb,
                                             (lds_void*)(Bs + chunk * 512), 16, 0, 0);
        }
        __syncthreads();

#pragma unroll
        for (int ks = 0; ks < 2; ++ks) {
            short8 af[4], bfr[4];
#pragma unroll
            for (int mt = 0; mt < 4; ++mt) {
                const int r = wm * 64 + mt * 16 + l16;
                const int p = (ks * 4 + quad) ^ (r & 7);
                af[mt] = *(const short8*)(As + r * 64 + p * 8);
            }
#pragma unroll
            for (int nt = 0; nt < 4; ++nt) {
                const int r = wn * 64 + nt * 16 + l16;
                const int p = (ks * 4 + quad) ^ (r & 7);
                bfr[nt] = *(const short8*)(Bs + r * 64 + p * 8);
            }
#pragma unroll
            for (int mt = 0; mt < 4; ++mt)
#pragma unroll
                for (int nt = 0; nt < 4; ++nt)
                    acc[mt][nt] = __builtin_amdgcn_mfma_f32_16x16x32_bf16(
                        af[mt], bfr[nt], acc[mt][nt], 0, 0, 0);
        }
    }

    // Epilogue. C/D layout: col = lane&15, row = quad*4 + reg  [m89-verified]
#pragma unroll
    for (int mt = 0; mt < 4; ++mt) {
        const int rb = m0 + wm * 64 + mt * 16 + quad * 4;
#pragma unroll
        for (int nt = 0; nt < 4; ++nt) {
            const int col = n0 + wn * 64 + nt * 16 + l16;
#pragma unroll
            for (int r = 0; r < 4; ++r) {
                const size_t idx = (size_t)(rb + r) * N + col;
                const float v = acc[mt][nt][r];
                if (EPI == 1) {
                    Cf[idx] = v + R[idx];
                } else {
                    Cf[idx] = v;
                }
            }
        }
    }
}

// ---------------- 128x128 bf16 GEMM, 4-buffer counted-vmcnt pipeline --------
// R6 post-mortem: 256^2 tiles cap every call site at <=256 workgroups -> 1
// block/CU (128 KB LDS) -> zero cross-block TLP; every drain exposed (MfmaUtil
// 13-29%, all pipes idle).  This kernel keeps R4's PROVEN pipeline (4 buffers,
// BK=32, prefetch depth 3, steady-state vmcnt(8) — never 0 in-loop; asm
// ds_read invisible to SIInsertWaitcnts + lgkmcnt(0)+sched_barrier, rule #18)
// but at 128^2/256-thread granularity: LDS = 4 x 16 KB = 64 KB -> 2 blocks/CU,
// grids 768-1024 blocks -> cross-block overlap hides the stalls (m114).
// Identical 4-loads/thread/tile ledger and swizzle algebra as R4 (0 conflicts).
// NT = K/(32*gridDim.z) must be %4==0 and >=8 (all call sites: 32).
// EPI: 2 = bf16 store gelu(acc), 4 = bf16 store, 5 = fp32 partial (z-sliced)
template <int EPI>
__global__ __launch_bounds__(256, 2) void gemm128p_bf16(const unsigned short* __restrict__ A,
                                                        const unsigned short* __restrict__ Wt,
                                                        float* __restrict__ Cf,
                                                        unsigned short* __restrict__ Cb,
                                                        int M, int N, int K) {
    __shared__ __align__(16) unsigned short Ls[4 * 8192];   // 64 KB

    const int tid  = threadIdx.x;
    const int wave = tid >> 6, lane = tid & 63;
    const int wm   = wave >> 1, wn = wave & 1;
    const int quad = lane >> 4, l16 = lane & 15;

    // bijective XCD swizzle over the (x,y) grid (nwg % 8 == 0 at all call sites)
    int bid = blockIdx.y * gridDim.x + blockIdx.x;
    const int cpx = (gridDim.x * gridDim.y) >> 3;
    bid = (bid & 7) * cpx + (bid >> 3);
    const int bx = bid % gridDim.x, by = bid / gridDim.x;
    const int m0 = by * 128, n0 = bx * 128;

    const int Kc   = K / gridDim.z;
    const int kbeg = blockIdx.z * Kc;
    const int NT   = Kc >> 5;                 // K-steps of 32 (==32 here)

    const int rr4 = lane >> 2;                // 0..15 row within 16-row group
    const int ch4 = lane & 3;                 // phys 16B chunk within 64B row

    const floatx4 z = {0.0f, 0.0f, 0.0f, 0.0f};
    floatx4 acc[4][4];
#pragma unroll
    for (int i = 0; i < 4; ++i)
#pragma unroll
        for (int j = 0; j < 4; ++j) acc[i][j] = z;

    // stage K-tile t (128x32 A + 128x32 B) into buffer bi: 2xA + 2xB DMA per
    // thread (identical count/ledger to R4).  Logical chunk c of row r stored
    // at phys c ^ ((r>>1)&3) via pre-swizzled source; LDS dest linear (#21).
    auto STAGE = [&](int t, int bi) {
        const int k0 = kbeg + t * 32;
#pragma unroll
        for (int i = 0; i < 2; ++i) {
            const int g    = wave * 2 + i;          // 16-row group 0..7
            const int grow = g * 16 + rr4;          // 0..127
            const int sch  = (ch4 ^ ((grow >> 1) & 3)) * 8;
            const unsigned short* ga = A  + (size_t)(m0 + grow) * K + k0 + sch;
            const unsigned short* gb = Wt + (size_t)(n0 + grow) * K + k0 + sch;
            unsigned short* la = Ls + bi * 8192 + g * 512;
            __builtin_amdgcn_global_load_lds((global_cvoid*)ga, (lds_void*)la,        16, 0, 0);
            __builtin_amdgcn_global_load_lds((global_cvoid*)gb, (lds_void*)(la + 4096), 16, 0, 0);
        }
    };

    // per-thread LDS byte addresses of frag 0 (buffer 0).  swizzle term
    // (r>>1)&3 == (l16>>1)&3 for all frags (mt*16, wm*64, wn*64 are 0 mod 8).
    const unsigned swz = (unsigned)(quad ^ ((l16 >> 1) & 3));
    const unsigned aA = lds_lo(Ls) + (unsigned)(wm * 64 + l16) * 64u + swz * 16u;
    const unsigned aB = lds_lo(Ls) + 8192u + (unsigned)(wn * 64 + l16) * 64u + swz * 16u;

    // one K-step.  C = LDS buffer (compile-time), PD = prefetch dest buffer.
#define GSTEP(T, C, PD, DOPF, WSTR, DOBAR)                                     \
    do {                                                                       \
        if (DOPF) STAGE((T) + 3, (PD));                                        \
        const unsigned aAc = aA + (C) * 16384u;                                \
        const unsigned aBc = aB + (C) * 16384u;                                \
        short8 af[4], bfr[4];                                                  \
        _Pragma("unroll")                                                      \
        for (int mt = 0; mt < 4; ++mt)                                         \
            asm volatile("ds_read_b128 %0, %1"                                 \
                         : "=v"(af[mt]) : "v"(aAc + mt * 1024u));              \
        _Pragma("unroll")                                                      \
        for (int nt = 0; nt < 4; ++nt)                                         \
            asm volatile("ds_read_b128 %0, %1"                                 \
                         : "=v"(bfr[nt]) : "v"(aBc + nt * 1024u));             \
        asm volatile("s_waitcnt lgkmcnt(0)" ::: "memory");                     \
        __builtin_amdgcn_sched_barrier(0);                                     \
        __builtin_amdgcn_s_setprio(1);                                         \
        _Pragma("unroll")                                                      \
        for (int mt = 0; mt < 4; ++mt)                                         \
            _Pragma("unroll")                                                  \
            for (int nt = 0; nt < 4; ++nt)                                     \
                acc[mt][nt] = __builtin_amdgcn_mfma_f32_16x16x32_bf16(         \
                    af[mt], bfr[nt], acc[mt][nt], 0, 0, 0);                    \
        __builtin_amdgcn_s_setprio(0);                                         \
        if (DOBAR) {                                                           \
            asm volatile("s_waitcnt " WSTR ::: "memory");                      \
            __builtin_amdgcn_s_barrier();                                      \
            __builtin_amdgcn_sched_barrier(0);                                 \
        }                                                                      \
    } while (0)

    // prologue: tiles 0,1,2 staged (12 loads); wait tile 0 (8 newest in flight)
    STAGE(0, 0);
    STAGE(1, 1);
    STAGE(2, 2);
    asm volatile("s_waitcnt vmcnt(8)" ::: "memory");
    __builtin_amdgcn_s_barrier();
    __builtin_amdgcn_sched_barrier(0);

    // steady state: step t reads buf t&3, stages t+3 into (t+3)&3, ends with
    // vmcnt(8) -> tile t+1 landed, tiles t+2/t+3 stay in flight (T3/T4).
    int t = 0;
    for (; t + 4 < NT; t += 4) {
        GSTEP(t + 0, 0, 3, true, "vmcnt(8)", true);
        GSTEP(t + 1, 1, 0, true, "vmcnt(8)", true);
        GSTEP(t + 2, 2, 1, true, "vmcnt(8)", true);
        GSTEP(t + 3, 3, 2, true, "vmcnt(8)", true);
    }
    // tail: t == NT-4
    GSTEP(t + 0, 0, 3, true,  "vmcnt(8)", true);   // stages tile NT-1
    GSTEP(t + 1, 1, 0, false, "vmcnt(4)", true);
    GSTEP(t + 2, 2, 1, false, "vmcnt(0)", true);
    GSTEP(t + 3, 3, 2, false, "vmcnt(0)", false);  // last: no wait/barrier
#undef GSTEP

    // Epilogue. C/D layout: col = lane&15, row = quad*4 + reg  [m89-verified]
    const size_t zoff = (size_t)blockIdx.z * M * N;
#pragma unroll
    for (int mt = 0; mt < 4; ++mt) {
        const int rb = m0 + wm * 64 + mt * 16 + quad * 4;
#pragma unroll
        for (int nt = 0; nt < 4; ++nt) {
            const int col = n0 + wn * 64 + nt * 16 + l16;
#pragma unroll
            for (int r = 0; r < 4; ++r) {
                const size_t idx = (size_t)(rb + r) * N + col;
                const float v = acc[mt][nt][r];
                if (EPI == 2) {
                    Cb[idx] = f2bf(gelu_f(v));
                } else if (EPI == 4) {
                    Cb[idx] = f2bf(v);
                } else {
                    Cf[zoff + idx] = v;   // split-K partial, coalesced
                }
            }
        }
    }
}

// ---------------- V transpose: proj v-part -> vt[(bh*64+d)][T] bf16 --------
__global__ __launch_bounds__(256) void vtrans_kernel(const unsigned short* __restrict__ proj,
                                                     unsigned short* __restrict__ vt) {
    __shared__ unsigned short L[64 * 72];
    const int bh = blockIdx.y, b = bh >> 4, h = bh & 15;
    const int st = blockIdx.x * 64;
    const int tid = threadIdx.x;
    {
        const int srel = tid >> 2, d16 = (tid & 3) * 16;
        const unsigned short* src =
            proj + (size_t)(b * T_SEQ + st + srel) * (3 * E_DIM) + 2 * E_DIM + h * 64 + d16;
        *(short8*)(L + srel * 72 + d16)     = *(const short8*)(src);
        *(short8*)(L + srel * 72 + d16 + 8) = *(const short8*)(src + 8);
    }
    __syncthreads();
    {
        const int d = tid >> 2, s16 = (tid & 3) * 16;
        short8 o0, o1;
#pragma unroll
        for (int j = 0; j < 8; ++j) {
            o0[j] = (short)L[(s16 + j) * 72 + d];
            o1[j] = (short)L[(s16 + 8 + j) * 72 + d];
        }
        unsigned short* dst = vt + (size_t)(bh * 64 + d) * T_SEQ + st + s16;
        *(short8*)dst       = o0;
        *(short8*)(dst + 8) = o1;
    }
}

// ---------------- Flash attention w/ fused RoPE, MFMA -----------------------
__device__ __forceinline__ void rope16(ushortx8 x0, ushortx8 x1, const float* tp,
                                       short8& y0, short8& y1) {
#pragma unroll
    for (int j = 0; j < 4; ++j) {
        const float c = tp[2 * j], s = tp[2 * j + 1];
        const float xr = bf2f(x0[2 * j]), xi = bf2f(x0[2 * j + 1]);
        y0[2 * j]     = (short)f2bf(xr * c - xi * s);
        y0[2 * j + 1] = (short)f2bf(xr * s + xi * c);
    }
#pragma unroll
    for (int j = 0; j < 4; ++j) {
        const float c = tp[8 + 2 * j], s = tp[8 + 2 * j + 1];
        const float xr = bf2f(x1[2 * j]), xi = bf2f(x1[2 * j + 1]);
        y1[2 * j]     = (short)f2bf(xr * c - xi * s);
        y1[2 * j + 1] = (short)f2bf(xr * s + xi * c);
    }
}

__global__ __launch_bounds__(256) void attn_kernel(const unsigned short* __restrict__ proj,
                                                   const unsigned short* __restrict__ vt,
                                                   const float* __restrict__ tab,
                                                   const int* __restrict__ ctxp,
                                                   unsigned short* __restrict__ o) {
    __shared__ unsigned short Qs[64 * 64];
    __shared__ unsigned short Ks[64 * 64];
    __shared__ unsigned short Vs[64 * 64];
    __shared__ unsigned short Ps[4][16 * 64];

    const int ctx = ctxp[0];
    const int tid = threadIdx.x;
    const int wave = tid >> 6, lane = tid & 63;
    const int quad = lane >> 4, l16 = lane & 15;
    const int bh = blockIdx.y, b = bh >> 4, h = bh & 15;
    const int t0 = blockIdx.x * 64;

    // ---- stage Q with RoPE (rows swizzled: chunk c at phys c^(row&7)) ----
    {
        const int r = tid >> 2, d16 = (tid & 3) * 16;
        const int pos = t0 + r;
        const unsigned short* src =
            proj + (size_t)(b * T_SEQ + pos) * (3 * E_DIM) + h * 64 + d16;
        ushortx8 x0 = *(const ushortx8*)src;
        ushortx8 x1 = *(const ushortx8*)(src + 8);
        const float* tp = tab + ((size_t)pos * 32 + (d16 >> 1)) * 2;
        short8 y0, y1;
        rope16(x0, x1, tp, y0, y1);
        const int c0 = (tid & 3) * 2;
        *(short8*)(Qs + r * 64 + ((c0)     ^ (r & 7)) * 8) = y0;
        *(short8*)(Qs + r * 64 + ((c0 + 1) ^ (r & 7)) * 8) = y1;
    }

    int first = t0 - (ctx - 1);
    if (first < 0) first = 0;
    const int first_base = first & ~63;

    float m[4] = {-1e30f, -1e30f, -1e30f, -1e30f};
    float l[4] = {0.0f, 0.0f, 0.0f, 0.0f};
    const floatx4 z = {0.0f, 0.0f, 0.0f, 0.0f};
    floatx4 accO[4] = {z, z, z, z};

    const int q_row0 = t0 + wave * 16 + quad * 4;   // abs query of reg r=0

    for (int s_base = first_base; s_base <= t0; s_base += 64) {
        __syncthreads();
        // ---- stage K with RoPE ----
        {
            const int r = tid >> 2, d16 = (tid & 3) * 16;
            const int pos = s_base + r;
            const unsigned short* src =
                proj + (size_t)(b * T_SEQ + pos) * (3 * E_DIM) + E_DIM + h * 64 + d16;
            ushortx8 x0 = *(const ushortx8*)src;
            ushortx8 x1 = *(const ushortx8*)(src + 8);
            const float* tp = tab + ((size_t)pos * 32 + (d16 >> 1)) * 2;
            short8 y0, y1;
            rope16(x0, x1, tp, y0, y1);
            const int c0 = (tid & 3) * 2;
            *(short8*)(Ks + r * 64 + ((c0)     ^ (r & 7)) * 8) = y0;
            *(short8*)(Ks + r * 64 + ((c0 + 1) ^ (r & 7)) * 8) = y1;
        }
        // ---- stage V^T tile via DMA (row d, cols s_base..+63, swizzled) ----
#pragma unroll
        for (int i = 0; i < 2; ++i) {
            const int chunk = (wave * 2 + i) * 64 + lane;   // 0..511
            const int d = chunk >> 3, c = chunk & 7;
            const unsigned short* gsrc =
                vt + (size_t)(bh * 64 + d) * T_SEQ + s_base + ((c ^ (d & 7)) * 8);
            __builtin_amdgcn_global_load_lds((global_cvoid*)gsrc,
                                             (lds_void*)(Vs + (wave * 2 + i) * 512),
                                             16, 0, 0);
        }
        __syncthreads();

        // ---- S = Q K^T (8 MFMA) ----
        floatx4 accS[4] = {z, z, z, z};
#pragma unroll
        for (int ks = 0; ks < 2; ++ks) {
            const int qrow = wave * 16 + l16;
            short8 aq = *(const short8*)(Qs + qrow * 64 + (((ks * 4 + quad) ^ (qrow & 7)) * 8));
#pragma unroll
            for (int nt = 0; nt < 4; ++nt) {
                const int kro = nt * 16 + l16;
                short8 bk = *(const short8*)(Ks + kro * 64 + (((ks * 4 + quad) ^ (kro & 7)) * 8));
                accS[nt] = __builtin_amdgcn_mfma_f32_16x16x32_bf16(aq, bk, accS[nt], 0, 0, 0);
            }
        }

        // ---- mask + online softmax (per q-row r = quad*4+reg) ----
        float p[4][4];      // [nt][r]
        float alpha[4];
#pragma unroll
        for (int r = 0; r < 4; ++r) {
            const int qa = q_row0 + r;
            float sv[4];
            float vmax = -1e30f;
#pragma unroll
            for (int nt = 0; nt < 4; ++nt) {
                const int sa = s_base + nt * 16 + l16;
                const int dd = qa - sa;
                const bool ok = (unsigned)dd < (unsigned)ctx;
                const float s = ok ? accS[nt][r] * 0.125f : -1e30f;
                sv[nt] = s;
                vmax = fmaxf(vmax, s);
            }
            vmax = fmaxf(vmax, __shfl_xor(vmax, 1));
            vmax = fmaxf(vmax, __shfl_xor(vmax, 2));
            vmax = fmaxf(vmax, __shfl_xor(vmax, 4));
            vmax = fmaxf(vmax, __shfl_xor(vmax, 8));
            const float mn = fmaxf(m[r], vmax);
            alpha[r] = __expf(m[r] - mn);
            float ps = 0.0f;
#pragma unroll
            for (int nt = 0; nt < 4; ++nt) {
                const float pe = (sv[nt] > -0.5e30f) ? __expf(sv[nt] - mn) : 0.0f;
                p[nt][r] = pe;
                ps += pe;
            }
            ps += __shfl_xor(ps, 1);
            ps += __shfl_xor(ps, 2);
            ps += __shfl_xor(ps, 4);
            ps += __shfl_xor(ps, 8);
            l[r] = l[r] * alpha[r] + ps;
            m[r] = mn;
        }

        // ---- write P to LDS (C-layout -> A-layout), rescale O ----
#pragma unroll
        for (int nt = 0; nt < 4; ++nt) {
#pragma unroll
            for (int r = 0; r < 4; ++r) {
                const int row = quad * 4 + r;
                const int col = nt * 16 + l16;
                Ps[wave][row * 64 + (((col >> 3) ^ (row & 7)) * 8) + (col & 7)] =
                    f2bf(p[nt][r]);
            }
        }
#pragma unroll
        for (int nt = 0; nt < 4; ++nt)
#pragma unroll
            for (int r = 0; r < 4; ++r) accO[nt][r] *= alpha[r];

        // ---- O += P V (8 MFMA) ----
#pragma unroll
        for (int ks = 0; ks < 2; ++ks) {
            short8 ap = *(const short8*)(&Ps[wave][l16 * 64 + (((ks * 4 + quad) ^ (l16 & 7)) * 8)]);
#pragma unroll
            for (int nt = 0; nt < 4; ++nt) {
                const int dr = nt * 16 + l16;
                short8 bv = *(const short8*)(Vs + dr * 64 + (((ks * 4 + quad) ^ (dr & 7)) * 8));
                accO[nt] = __builtin_amdgcn_mfma_f32_16x16x32_bf16(ap, bv, accO[nt], 0, 0, 0);
            }
        }
    }

    // ---- epilogue: normalize, store bf16 to (B,T,E) ----
    float inv[4];
#pragma unroll
    for (int r = 0; r < 4; ++r) inv[r] = 1.0f / l[r];
#pragma unroll
    for (int nt = 0; nt < 4; ++nt) {
#pragma unroll
        for (int r = 0; r < 4; ++r) {
            const int t = q_row0 + r;
            o[(size_t)(b * T_SEQ + t) * E_DIM + h * 64 + nt * 16 + l16] =
                f2bf(accO[nt][r] * inv[r]);
        }
    }
}

// ---------------------------------------------------------------------------
extern "C" void kernel_launch(void* const* d_in, const int* in_sizes, int n_in,
                              void* d_out, int out_size, void* d_ws, size_t ws_size,
                              hipStream_t stream) {
    const float* x          = (const float*)d_in[0];
    const float* in_proj_w  = (const float*)d_in[1];
    const float* out_proj_w = (const float*)d_in[2];
    const float* ln1_g      = (const float*)d_in[3];
    const float* ln1_b      = (const float*)d_in[4];
    const float* ln2_g      = (const float*)d_in[5];
    const float* ln2_b      = (const float*)d_in[6];
    const float* w1         = (const float*)d_in[7];
    const float* w2         = (const float*)d_in[8];
    const int*   ctx        = (const int*)d_in[9];
    float* out = (float*)d_out;
    float* ws  = (float*)d_ws;

    // Workspace layout (byte offsets); split-K partials (bytes 0..64M) overlay
    // regions that are ALL dead during the MLP2 GEMM:
    //   0.. 6M  wqkv_b | 6..8M wout_b | 8..16M w1_b | 16..24M h_b
    //  24..32M  obuf_b | 32..56M proj_b | 56..64M vt_b
    //  64..96M  mid_b  | 96..104M w2_b | 104..104.5M tab
    const size_t MEG = 1024u * 1024u;
    unsigned short* u = (unsigned short*)ws;
    unsigned short* wqkv_b = u;                 // bytes   0..6
    unsigned short* wout_b = u + 3 * MEG;       // bytes   6..8
    unsigned short* w1_b   = u + 4 * MEG;       // bytes   8..16
    unsigned short* h_b    = u + 8 * MEG;       // bytes  16..24
    unsigned short* obuf_b = u + 12 * MEG;      // bytes  24..32
    unsigned short* proj_b = u + 16 * MEG;      // bytes  32..56
    unsigned short* vt_b   = u + 28 * MEG;      // bytes  56..64
    unsigned short* mid_b  = u + 32 * MEG;      // bytes  64..96
    unsigned short* w2_b   = u + 48 * MEG;      // bytes  96..104
    float* tab  = ws + 26 * MEG;                // bytes 104..104.5
    float* part = ws;                           // 4 slices x 16 MB, bytes 0..64

    // 0+1. fused: weights->bf16, rope table, h1 = LN1(x)
    prep_kernel<<<16640, 256, 0, stream>>>(in_proj_w, out_proj_w, w1, w2,
                                           x, ln1_g, ln1_b,
                                           wqkv_b, wout_b, w1_b, w2_b, h_b, tab);
    // 2. proj = h1 @ in_proj_w^T -> bf16   (128², 768 blocks, 2 blocks/CU)
    gemm128p_bf16<4><<<dim3(3 * E_DIM / 128, M_ROWS / 128), 256, 0, stream>>>(
        h_b, wqkv_b, nullptr, proj_b, M_ROWS, 3 * E_DIM, E_DIM);
    // 3. V^T
    vtrans_kernel<<<dim3(T_SEQ / 64, B_BATCH * H_HEADS), 256, 0, stream>>>(proj_b, vt_b);
    // 4. flash attention (fused RoPE) -> obuf bf16 (B,T,E)
    attn_kernel<<<dim3(T_SEQ / 64, B_BATCH * H_HEADS), 256, 0, stream>>>(
        proj_b, vt_b, tab, ctx, obuf_b);
    // 5. out = x + obuf @ out_proj_w^T (fused residual store; m97 128² kernel)
    gemm_bf16<1><<<dim3(E_DIM / 128, M_ROWS / 128), 256, 0, stream>>>(
        obuf_b, wout_b, x, out, nullptr, M_ROWS, E_DIM, E_DIM);
    // 6. h2 = LN2(out) -> bf16
    ln_kernel<<<M_ROWS, 256, 0, stream>>>(out, ln2_g, ln2_b, h_b);
    // 7. mid = gelu(h2 @ w1^T) -> bf16   (128², 1024 blocks)
    gemm128p_bf16<2><<<dim3(F_DIM / 128, M_ROWS / 128), 256, 0, stream>>>(
        h_b, w1_b, nullptr, mid_b, M_ROWS, F_DIM, E_DIM);
    // 8. part[z] = mid @ w2^T (split-K=4, Kc=1024, 1024 blocks), out += Σ part
    gemm128p_bf16<5><<<dim3(E_DIM / 128, M_ROWS / 128, 4), 256, 0, stream>>>(
        mid_b, w2_b, part, nullptr, M_ROWS, E_DIM, F_DIM);
    reduce4_kernel<<<M_ROWS * E_DIM / 1024, 256, 0, stream>>>(
        part, out, M_ROWS * E_DIM);
}

// Round 14
// 305.764 us; speedup vs baseline: 1.5858x; 1.0450x over previous
//
#include <hip/hip_runtime.h>
#include <math.h>

// Problem constants (from reference setup_inputs)
#define B_BATCH 2
#define T_SEQ   2048
#define E_DIM   1024
#define H_HEADS 16
#define D_HEAD  64
#define F_DIM   4096
#define M_ROWS  (B_BATCH * T_SEQ)   // 4096

typedef __attribute__((ext_vector_type(8))) short short8;       // bf16x8 MFMA frag
typedef __attribute__((ext_vector_type(4))) float floatx4;      // MFMA acc
typedef __attribute__((ext_vector_type(8))) unsigned short ushortx8;

typedef __attribute__((address_space(1))) const void global_cvoid;
typedef __attribute__((address_space(3))) void lds_void;

__device__ __forceinline__ unsigned short f2bf(float f) {      // RNE f32->bf16
    unsigned u = __float_as_uint(f);
    u += 0x7fffu + ((u >> 16) & 1u);
    return (unsigned short)(u >> 16);
}
__device__ __forceinline__ float bf2f(unsigned short h) {
    return __uint_as_float(((unsigned)h) << 16);
}

// low 32 bits of a generic pointer to __shared__ = LDS byte offset (gfx9+)
__device__ __forceinline__ unsigned lds_lo(const void* p) {
    return (unsigned)(unsigned long long)p;
}

// gelu via A&S 7.1.26 erf: |err| <= 1.5e-7, ~14 VALU ops, no divergence.
__device__ __forceinline__ float gelu_f(float v) {
    const float x = fabsf(v) * 0.70710678118654752f;
    const float t = __builtin_amdgcn_rcpf(__builtin_fmaf(0.3275911f, x, 1.0f));
    float p = __builtin_fmaf(1.061405429f, t, -1.453152027f);
    p = __builtin_fmaf(p, t, 1.421413741f);
    p = __builtin_fmaf(p, t, -0.284496736f);
    p = __builtin_fmaf(p, t, 0.254829592f);
    p *= t;
    const float e = __expf(-x * x);
    float er = __builtin_fmaf(-p, e, 1.0f);          // erf(|x|)
    er = copysignf(er, v);
    return 0.5f * v * (1.0f + er);
}

__device__ __forceinline__ float waveReduceSum(float v) {
#pragma unroll
    for (int off = 32; off > 0; off >>= 1) v += __shfl_xor(v, off, 64);
    return v;
}

// ---------------- LayerNorm row body (shared by prep / ln_kernel) ----------
__device__ __forceinline__ void ln_row(const float* __restrict__ x,
                                       const float* __restrict__ g,
                                       const float* __restrict__ b,
                                       unsigned short* __restrict__ out, int row) {
    const float* xr = x + (size_t)row * E_DIM;
    float4 v = ((const float4*)xr)[threadIdx.x];
    float s  = v.x + v.y + v.z + v.w;
    float sq = v.x * v.x + v.y * v.y + v.z * v.z + v.w * v.w;

    __shared__ float red[8];
    float ws_ = waveReduceSum(s);
    float wq  = waveReduceSum(sq);
    int wid = threadIdx.x >> 6;
    if ((threadIdx.x & 63) == 0) { red[wid] = ws_; red[wid + 4] = wq; }
    __syncthreads();
    float ts = red[0] + red[1] + red[2] + red[3];
    float tq = red[4] + red[5] + red[6] + red[7];
    float mean = ts * (1.0f / E_DIM);
    float var  = tq * (1.0f / E_DIM) - mean * mean;
    float inv  = rsqrtf(var + 1e-5f);

    float4 gv = ((const float4*)g)[threadIdx.x];
    float4 bv = ((const float4*)b)[threadIdx.x];
    ushort4 o;
    o.x = f2bf((v.x - mean) * inv * gv.x + bv.x);
    o.y = f2bf((v.y - mean) * inv * gv.y + bv.y);
    o.z = f2bf((v.z - mean) * inv * gv.z + bv.z);
    o.w = f2bf((v.w - mean) * inv * gv.w + bv.w);
    ((ushort4*)(out + (size_t)row * E_DIM))[threadIdx.x] = o;
}

__global__ __launch_bounds__(256) void ln_kernel(const float* __restrict__ x,
                                                 const float* __restrict__ g,
                                                 const float* __restrict__ b,
                                                 unsigned short* __restrict__ out) {
    ln_row(x, g, b, out, blockIdx.x);
}

// ---------------- fused prep: 4x weight cvt + rope table + LN1 -------------
// block ranges (1024 elems per cvt block):
//  [0,3072) wqkv | [3072,4096) wout | [4096,8192) w1 | [8192,12288) w2
//  [12288,12544) rope tab | [12544,16640) ln1 rows
__global__ __launch_bounds__(256) void prep_kernel(
    const float* __restrict__ in_proj_w, const float* __restrict__ out_proj_w,
    const float* __restrict__ w1, const float* __restrict__ w2,
    const float* __restrict__ x, const float* __restrict__ ln1_g,
    const float* __restrict__ ln1_b,
    unsigned short* __restrict__ wqkv_b, unsigned short* __restrict__ wout_b,
    unsigned short* __restrict__ w1_b, unsigned short* __restrict__ w2_b,
    unsigned short* __restrict__ h_b, float* __restrict__ tab) {
    const int blk = blockIdx.x;
    if (blk < 12288) {
        const float* src; unsigned short* dst; int base;
        if (blk < 3072)      { src = in_proj_w;  dst = wqkv_b; base = blk; }
        else if (blk < 4096) { src = out_proj_w; dst = wout_b; base = blk - 3072; }
        else if (blk < 8192) { src = w1;         dst = w1_b;   base = blk - 4096; }
        else                 { src = w2;         dst = w2_b;   base = blk - 8192; }
        const int i = (base * 256 + threadIdx.x) * 4;
        float4 v = *(const float4*)(src + i);
        ushort4 o;
        o.x = f2bf(v.x); o.y = f2bf(v.y); o.z = f2bf(v.z); o.w = f2bf(v.w);
        *(ushort4*)(dst + i) = o;
    } else if (blk < 12544) {
        const int idx = (blk - 12288) * 256 + threadIdx.x;   // 0..65535
        const int pos = idx >> 5, i = idx & 31;
        const float invf = powf(10000.0f, -(float)i / 32.0f);
        const float ang = (float)pos * invf;
        tab[idx * 2]     = cosf(ang);
        tab[idx * 2 + 1] = sinf(ang);
    } else {
        ln_row(x, ln1_g, ln1_b, h_b, blk - 12544);
    }
}

// ---------------- split-K reduce: out += p0 + p1 --------------------------
__global__ __launch_bounds__(256) void reduce2_kernel(const float* __restrict__ p,
                                                      float* __restrict__ out, int n) {
    const int i = (blockIdx.x * 256 + threadIdx.x) * 4;
    if (i >= n) return;
    float4 a  = *(const float4*)(out + i);
    float4 b0 = *(const float4*)(p + i);
    float4 b1 = *(const float4*)(p + (size_t)n + i);
    a.x += b0.x + b1.x;
    a.y += b0.y + b1.y;
    a.z += b0.z + b1.z;
    a.w += b0.w + b1.w;
    *(float4*)(out + i) = a;
}

// ---------------- 128x128 bf16 MFMA GEMM (out_proj; m97 structure) ----------
// EPI: 1 = fp32 store acc + R
template <int EPI>
__global__ __launch_bounds__(256) void gemm_bf16(const unsigned short* __restrict__ A,
                                                 const unsigned short* __restrict__ Wt,
                                                 const float* __restrict__ R,
                                                 float* __restrict__ Cf,
                                                 unsigned short* __restrict__ Cb,
                                                 int M, int N, int K) {
    __shared__ unsigned short As[128 * 64];
    __shared__ unsigned short Bs[128 * 64];
    const int tid  = threadIdx.x;
    const int wave = tid >> 6, lane = tid & 63;
    const int wm   = wave >> 1, wn = wave & 1;
    const int quad = lane >> 4, l16 = lane & 15;
    const int m0 = blockIdx.y * 128, n0 = blockIdx.x * 128;
    const int Kc   = K / gridDim.z;
    const int kbeg = blockIdx.z * Kc;

    const int row_rel = lane >> 3;   // 0..7: row within 8-row DMA chunk
    const int ch      = lane & 7;    // phys 16B chunk within row

    const floatx4 z = {0.0f, 0.0f, 0.0f, 0.0f};
    floatx4 acc[4][4];
#pragma unroll
    for (int i = 0; i < 4; ++i)
#pragma unroll
        for (int j = 0; j < 4; ++j) acc[i][j] = z;

    for (int k0 = kbeg; k0 < kbeg + Kc; k0 += 64) {
        __syncthreads();
#pragma unroll
        for (int i = 0; i < 4; ++i) {
            const int chunk = wave * 4 + i;          // 0..15 (8 rows each)
            const int grow  = chunk * 8 + row_rel;   // tile row 0..127
            const int lch   = ch ^ (grow & 7);       // swizzled source chunk
            const unsigned short* ga = A  + (size_t)(m0 + grow) * K + k0 + lch * 8;
            const unsigned short* gb = Wt + (size_t)(n0 + grow) * K + k0 + lch * 8;
            __builtin_amdgcn_global_load_lds((global_cvoid*)ga,
                                             (lds_void*)(As + chunk * 512), 16, 0, 0);
            __builtin_amdgcn_global_load_lds((global_cvoid*)gb,
                                             (lds_void*)(Bs + chunk * 512), 16, 0, 0);
        }
        __syncthreads();

#pragma unroll
        for (int ks = 0; ks < 2; ++ks) {
            short8 af[4], bfr[4];
#pragma unroll
            for (int mt = 0; mt < 4; ++mt) {
                const int r = wm * 64 + mt * 16 + l16;
                const int p = (ks * 4 + quad) ^ (r & 7);
                af[mt] = *(const short8*)(As + r * 64 + p * 8);
            }
#pragma unroll
            for (int nt = 0; nt < 4; ++nt) {
                const int r = wn * 64 + nt * 16 + l16;
                const int p = (ks * 4 + quad) ^ (r & 7);
                bfr[nt] = *(const short8*)(Bs + r * 64 + p * 8);
            }
#pragma unroll
            for (int mt = 0; mt < 4; ++mt)
#pragma unroll
                for (int nt = 0; nt < 4; ++nt)
                    acc[mt][nt] = __builtin_amdgcn_mfma_f32_16x16x32_bf16(
                        af[mt], bfr[nt], acc[mt][nt], 0, 0, 0);
        }
    }

    // Epilogue. C/D layout: col = lane&15, row = quad*4 + reg  [m89-verified]
#pragma unroll
    for (int mt = 0; mt < 4; ++mt) {
        const int rb = m0 + wm * 64 + mt * 16 + quad * 4;
#pragma unroll
        for (int nt = 0; nt < 4; ++nt) {
            const int col = n0 + wn * 64 + nt * 16 + l16;
#pragma unroll
            for (int r = 0; r < 4; ++r) {
                const size_t idx = (size_t)(rb + r) * N + col;
                const float v = acc[mt][nt][r];
                if (EPI == 1) {
                    Cf[idx] = v + R[idx];
                } else {
                    Cf[idx] = v;
                }
            }
        }
    }
}

// ---------------- 128x128 bf16 GEMM, 4-buffer counted-vmcnt pipeline --------
// R8 post-mortem: pipeline fine (conflicts 0, VGPR 88) but FETCH tripled to
// 119 MB (vs 37.8 at 256² tile) -> MLP1 became L2-miss-traffic-bound at
// ~3 TB/s.  Cause: %8 XCD swizzle gives each XCD bx≡x(mod 8) over ALL by ->
// per-XCD working set = all-A (8MB) + 4 B-panels = 9 MB >> 4 MB L2 -> thrash.
// Fix: XCD-SLAB rasterization — each XCD owns a 4-row slab (gridDim.y == 32
// at every call site), traversed column-major: co-resident 64 blocks/XCD span
// 4 by x ~16 bx -> ~1 MB A (pinned) + ~4 MB B window ≈ L2 capacity.
// Pipeline unchanged from R8 (4 buf, BK=32, depth-3, vmcnt(8) steady; asm
// ds_read + lgkmcnt(0) + sched_barrier — rule #18).
// NT = K/(32*gridDim.z) must be %4==0 and >=8 (call sites: 32, 32, 64).
// EPI: 2 = bf16 store gelu(acc), 4 = bf16 store, 5 = fp32 partial (z-sliced)
template <int EPI>
__global__ __launch_bounds__(256, 2) void gemm128p_bf16(const unsigned short* __restrict__ A,
                                                        const unsigned short* __restrict__ Wt,
                                                        float* __restrict__ Cf,
                                                        unsigned short* __restrict__ Cb,
                                                        int M, int N, int K) {
    __shared__ __align__(16) unsigned short Ls[4 * 8192];   // 64 KB

    const int tid  = threadIdx.x;
    const int wave = tid >> 6, lane = tid & 63;
    const int wm   = wave >> 1, wn = wave & 1;
    const int quad = lane >> 4, l16 = lane & 15;

    // XCD-slab rasterization (bijective; requires gridDim.y == 32):
    // HW slot orig lands on XCD orig%8 (dispatch is x-major round-robin; z
    // offset is a multiple of 256 ≡ 0 mod 8).  XCD x covers by ∈ [4x, 4x+4),
    // column-major in bx so the B-window slides while the A slab stays hot.
    const int orig = blockIdx.y * gridDim.x + blockIdx.x;
    const int xcd  = orig & 7;
    const int j    = orig >> 3;             // 0 .. gridDim.x*4 - 1
    const int bx   = j >> 2;
    const int by   = xcd * 4 + (j & 3);
    const int m0 = by * 128, n0 = bx * 128;

    const int Kc   = K / gridDim.z;
    const int kbeg = blockIdx.z * Kc;
    const int NT   = Kc >> 5;                 // K-steps of 32

    const int rr4 = lane >> 2;                // 0..15 row within 16-row group
    const int ch4 = lane & 3;                 // phys 16B chunk within 64B row

    const floatx4 z = {0.0f, 0.0f, 0.0f, 0.0f};
    floatx4 acc[4][4];
#pragma unroll
    for (int i = 0; i < 4; ++i)
#pragma unroll
        for (int j2 = 0; j2 < 4; ++j2) acc[i][j2] = z;

    // stage K-tile t (128x32 A + 128x32 B) into buffer bi: 2xA + 2xB DMA per
    // thread.  Logical chunk c of row r stored at phys c ^ ((r>>1)&3) via
    // pre-swizzled source; LDS dest linear (#21).
    auto STAGE = [&](int t, int bi) {
        const int k0 = kbeg + t * 32;
#pragma unroll
        for (int i = 0; i < 2; ++i) {
            const int g    = wave * 2 + i;          // 16-row group 0..7
            const int grow = g * 16 + rr4;          // 0..127
            const int sch  = (ch4 ^ ((grow >> 1) & 3)) * 8;
            const unsigned short* ga = A  + (size_t)(m0 + grow) * K + k0 + sch;
            const unsigned short* gb = Wt + (size_t)(n0 + grow) * K + k0 + sch;
            unsigned short* la = Ls + bi * 8192 + g * 512;
            __builtin_amdgcn_global_load_lds((global_cvoid*)ga, (lds_void*)la,        16, 0, 0);
            __builtin_amdgcn_global_load_lds((global_cvoid*)gb, (lds_void*)(la + 4096), 16, 0, 0);
        }
    };

    // per-thread LDS byte addresses of frag 0 (buffer 0).  swizzle term
    // (r>>1)&3 == (l16>>1)&3 for all frags (mt*16, wm*64, wn*64 are 0 mod 8).
    const unsigned swz = (unsigned)(quad ^ ((l16 >> 1) & 3));
    const unsigned aA = lds_lo(Ls) + (unsigned)(wm * 64 + l16) * 64u + swz * 16u;
    const unsigned aB = lds_lo(Ls) + 8192u + (unsigned)(wn * 64 + l16) * 64u + swz * 16u;

    // one K-step.  C = LDS buffer (compile-time), PD = prefetch dest buffer.
#define GSTEP(T, C, PD, DOPF, WSTR, DOBAR)                                     \
    do {                                                                       \
        if (DOPF) STAGE((T) + 3, (PD));                                        \
        const unsigned aAc = aA + (C) * 16384u;                                \
        const unsigned aBc = aB + (C) * 16384u;                                \
        short8 af[4], bfr[4];                                                  \
        _Pragma("unroll")                                                      \
        for (int mt = 0; mt < 4; ++mt)                                         \
            asm volatile("ds_read_b128 %0, %1"                                 \
                         : "=v"(af[mt]) : "v"(aAc + mt * 1024u));              \
        _Pragma("unroll")                                                      \
        for (int nt = 0; nt < 4; ++nt)                                         \
            asm volatile("ds_read_b128 %0, %1"                                 \
                         : "=v"(bfr[nt]) : "v"(aBc + nt * 1024u));             \
        asm volatile("s_waitcnt lgkmcnt(0)" ::: "memory");                     \
        __builtin_amdgcn_sched_barrier(0);                                     \
        __builtin_amdgcn_s_setprio(1);                                         \
        _Pragma("unroll")                                                      \
        for (int mt = 0; mt < 4; ++mt)                                         \
            _Pragma("unroll")                                                  \
            for (int nt = 0; nt < 4; ++nt)                                     \
                acc[mt][nt] = __builtin_amdgcn_mfma_f32_16x16x32_bf16(         \
                    af[mt], bfr[nt], acc[mt][nt], 0, 0, 0);                    \
        __builtin_amdgcn_s_setprio(0);                                         \
        if (DOBAR) {                                                           \
            asm volatile("s_waitcnt " WSTR ::: "memory");                      \
            __builtin_amdgcn_s_barrier();                                      \
            __builtin_amdgcn_sched_barrier(0);                                 \
        }                                                                      \
    } while (0)

    // prologue: tiles 0,1,2 staged (12 loads); wait tile 0 (8 newest in flight)
    STAGE(0, 0);
    STAGE(1, 1);
    STAGE(2, 2);
    asm volatile("s_waitcnt vmcnt(8)" ::: "memory");
    __builtin_amdgcn_s_barrier();
    __builtin_amdgcn_sched_barrier(0);

    // steady state: step t reads buf t&3, stages t+3 into (t+3)&3, ends with
    // vmcnt(8) -> tile t+1 landed, tiles t+2/t+3 stay in flight (T3/T4).
    int t = 0;
    for (; t + 4 < NT; t += 4) {
        GSTEP(t + 0, 0, 3, true, "vmcnt(8)", true);
        GSTEP(t + 1, 1, 0, true, "vmcnt(8)", true);
        GSTEP(t + 2, 2, 1, true, "vmcnt(8)", true);
        GSTEP(t + 3, 3, 2, true, "vmcnt(8)", true);
    }
    // tail: t == NT-4
    GSTEP(t + 0, 0, 3, true,  "vmcnt(8)", true);   // stages tile NT-1
    GSTEP(t + 1, 1, 0, false, "vmcnt(4)", true);
    GSTEP(t + 2, 2, 1, false, "vmcnt(0)", true);
    GSTEP(t + 3, 3, 2, false, "vmcnt(0)", false);  // last: no wait/barrier
#undef GSTEP

    // Epilogue. C/D layout: col = lane&15, row = quad*4 + reg  [m89-verified]
    const size_t zoff = (size_t)blockIdx.z * M * N;
#pragma unroll
    for (int mt = 0; mt < 4; ++mt) {
        const int rb = m0 + wm * 64 + mt * 16 + quad * 4;
#pragma unroll
        for (int nt = 0; nt < 4; ++nt) {
            const int col = n0 + wn * 64 + nt * 16 + l16;
#pragma unroll
            for (int r = 0; r < 4; ++r) {
                const size_t idx = (size_t)(rb + r) * N + col;
                const float v = acc[mt][nt][r];
                if (EPI == 2) {
                    Cb[idx] = f2bf(gelu_f(v));
                } else if (EPI == 4) {
                    Cb[idx] = f2bf(v);
                } else {
                    Cf[zoff + idx] = v;   // split-K partial, coalesced
                }
            }
        }
    }
}

// ---------------- V transpose: proj v-part -> vt[(bh*64+d)][T] bf16 --------
__global__ __launch_bounds__(256) void vtrans_kernel(const unsigned short* __restrict__ proj,
                                                     unsigned short* __restrict__ vt) {
    __shared__ unsigned short L[64 * 72];
    const int bh = blockIdx.y, b = bh >> 4, h = bh & 15;
    const int st = blockIdx.x * 64;
    const int tid = threadIdx.x;
    {
        const int srel = tid >> 2, d16 = (tid & 3) * 16;
        const unsigned short* src =
            proj + (size_t)(b * T_SEQ + st + srel) * (3 * E_DIM) + 2 * E_DIM + h * 64 + d16;
        *(short8*)(L + srel * 72 + d16)     = *(const short8*)(src);
        *(short8*)(L + srel * 72 + d16 + 8) = *(const short8*)(src + 8);
    }
    __syncthreads();
    {
        const int d = tid >> 2, s16 = (tid & 3) * 16;
        short8 o0, o1;
#pragma unroll
        for (int j = 0; j < 8; ++j) {
            o0[j] = (short)L[(s16 + j) * 72 + d];
            o1[j] = (short)L[(s16 + 8 + j) * 72 + d];
        }
        unsigned short* dst = vt + (size_t)(bh * 64 + d) * T_SEQ + st + s16;
        *(short8*)dst       = o0;
        *(short8*)(dst + 8) = o1;
    }
}

// ---------------- Flash attention w/ fused RoPE, MFMA -----------------------
__device__ __forceinline__ void rope16(ushortx8 x0, ushortx8 x1, const float* tp,
                                       short8& y0, short8& y1) {
#pragma unroll
    for (int j = 0; j < 4; ++j) {
        const float c = tp[2 * j], s = tp[2 * j + 1];
        const float xr = bf2f(x0[2 * j]), xi = bf2f(x0[2 * j + 1]);
        y0[2 * j]     = (short)f2bf(xr * c - xi * s);
        y0[2 * j + 1] = (short)f2bf(xr * s + xi * c);
    }
#pragma unroll
    for (int j = 0; j < 4; ++j) {
        const float c = tp[8 + 2 * j], s = tp[8 + 2 * j + 1];
        const float xr = bf2f(x1[2 * j]), xi = bf2f(x1[2 * j + 1]);
        y1[2 * j]     = (short)f2bf(xr * c - xi * s);
        y1[2 * j + 1] = (short)f2bf(xr * s + xi * c);
    }
}

__global__ __launch_bounds__(256) void attn_kernel(const unsigned short* __restrict__ proj,
                                                   const unsigned short* __restrict__ vt,
                                                   const float* __restrict__ tab,
                                                   const int* __restrict__ ctxp,
                                                   unsigned short* __restrict__ o) {
    __shared__ unsigned short Qs[64 * 64];
    __shared__ unsigned short Ks[64 * 64];
    __shared__ unsigned short Vs[64 * 64];
    __shared__ unsigned short Ps[4][16 * 64];

    const int ctx = ctxp[0];
    const int tid = threadIdx.x;
    const int wave = tid >> 6, lane = tid & 63;
    const int quad = lane >> 4, l16 = lane & 15;
    const int bh = blockIdx.y, b = bh >> 4, h = bh & 15;
    const int t0 = blockIdx.x * 64;

    // ---- stage Q with RoPE (rows swizzled: chunk c at phys c^(row&7)) ----
    {
        const int r = tid >> 2, d16 = (tid & 3) * 16;
        const int pos = t0 + r;
        const unsigned short* src =
            proj + (size_t)(b * T_SEQ + pos) * (3 * E_DIM) + h * 64 + d16;
        ushortx8 x0 = *(const ushortx8*)src;
        ushortx8 x1 = *(const ushortx8*)(src + 8);
        const float* tp = tab + ((size_t)pos * 32 + (d16 >> 1)) * 2;
        short8 y0, y1;
        rope16(x0, x1, tp, y0, y1);
        const int c0 = (tid & 3) * 2;
        *(short8*)(Qs + r * 64 + ((c0)     ^ (r & 7)) * 8) = y0;
        *(short8*)(Qs + r * 64 + ((c0 + 1) ^ (r & 7)) * 8) = y1;
    }

    int first = t0 - (ctx - 1);
    if (first < 0) first = 0;
    const int first_base = first & ~63;

    float m[4] = {-1e30f, -1e30f, -1e30f, -1e30f};
    float l[4] = {0.0f, 0.0f, 0.0f, 0.0f};
    const floatx4 z = {0.0f, 0.0f, 0.0f, 0.0f};
    floatx4 accO[4] = {z, z, z, z};

    const int q_row0 = t0 + wave * 16 + quad * 4;   // abs query of reg r=0

    for (int s_base = first_base; s_base <= t0; s_base += 64) {
        __syncthreads();
        // ---- stage K with RoPE ----
        {
            const int r = tid >> 2, d16 = (tid & 3) * 16;
            const int pos = s_base + r;
            const unsigned short* src =
                proj + (size_t)(b * T_SEQ + pos) * (3 * E_DIM) + E_DIM + h * 64 + d16;
            ushortx8 x0 = *(const ushortx8*)src;
            ushortx8 x1 = *(const ushortx8*)(src + 8);
            const float* tp = tab + ((size_t)pos * 32 + (d16 >> 1)) * 2;
            short8 y0, y1;
            rope16(x0, x1, tp, y0, y1);
            const int c0 = (tid & 3) * 2;
            *(short8*)(Ks + r * 64 + ((c0)     ^ (r & 7)) * 8) = y0;
            *(short8*)(Ks + r * 64 + ((c0 + 1) ^ (r & 7)) * 8) = y1;
        }
        // ---- stage V^T tile via DMA (row d, cols s_base..+63, swizzled) ----
#pragma unroll
        for (int i = 0; i < 2; ++i) {
            const int chunk = (wave * 2 + i) * 64 + lane;   // 0..511
            const int d = chunk >> 3, c = chunk & 7;
            const unsigned short* gsrc =
                vt + (size_t)(bh * 64 + d) * T_SEQ + s_base + ((c ^ (d & 7)) * 8);
            __builtin_amdgcn_global_load_lds((global_cvoid*)gsrc,
                                             (lds_void*)(Vs + (wave * 2 + i) * 512),
                                             16, 0, 0);
        }
        __syncthreads();

        // ---- S = Q K^T (8 MFMA) ----
        floatx4 accS[4] = {z, z, z, z};
#pragma unroll
        for (int ks = 0; ks < 2; ++ks) {
            const int qrow = wave * 16 + l16;
            short8 aq = *(const short8*)(Qs + qrow * 64 + (((ks * 4 + quad) ^ (qrow & 7)) * 8));
#pragma unroll
            for (int nt = 0; nt < 4; ++nt) {
                const int kro = nt * 16 + l16;
                short8 bk = *(const short8*)(Ks + kro * 64 + (((ks * 4 + quad) ^ (kro & 7)) * 8));
                accS[nt] = __builtin_amdgcn_mfma_f32_16x16x32_bf16(aq, bk, accS[nt], 0, 0, 0);
            }
        }

        // ---- mask + online softmax (per q-row r = quad*4+reg) ----
        float p[4][4];      // [nt][r]
        float alpha[4];
#pragma unroll
        for (int r = 0; r < 4; ++r) {
            const int qa = q_row0 + r;
            float sv[4];
            float vmax = -1e30f;
#pragma unroll
            for (int nt = 0; nt < 4; ++nt) {
                const int sa = s_base + nt * 16 + l16;
                const int dd = qa - sa;
                const bool ok = (unsigned)dd < (unsigned)ctx;
                const float s = ok ? accS[nt][r] * 0.125f : -1e30f;
                sv[nt] = s;
                vmax = fmaxf(vmax, s);
            }
            vmax = fmaxf(vmax, __shfl_xor(vmax, 1));
            vmax = fmaxf(vmax, __shfl_xor(vmax, 2));
            vmax = fmaxf(vmax, __shfl_xor(vmax, 4));
            vmax = fmaxf(vmax, __shfl_xor(vmax, 8));
            const float mn = fmaxf(m[r], vmax);
            alpha[r] = __expf(m[r] - mn);
            float ps = 0.0f;
#pragma unroll
            for (int nt = 0; nt < 4; ++nt) {
                const float pe = (sv[nt] > -0.5e30f) ? __expf(sv[nt] - mn) : 0.0f;
                p[nt][r] = pe;
                ps += pe;
            }
            ps += __shfl_xor(ps, 1);
            ps += __shfl_xor(ps, 2);
            ps += __shfl_xor(ps, 4);
            ps += __shfl_xor(ps, 8);
            l[r] = l[r] * alpha[r] + ps;
            m[r] = mn;
        }

        // ---- write P to LDS (C-layout -> A-layout), rescale O ----
#pragma unroll
        for (int nt = 0; nt < 4; ++nt) {
#pragma unroll
            for (int r = 0; r < 4; ++r) {
                const int row = quad * 4 + r;
                const int col = nt * 16 + l16;
                Ps[wave][row * 64 + (((col >> 3) ^ (row & 7)) * 8) + (col & 7)] =
                    f2bf(p[nt][r]);
            }
        }
#pragma unroll
        for (int nt = 0; nt < 4; ++nt)
#pragma unroll
            for (int r = 0; r < 4; ++r) accO[nt][r] *= alpha[r];

        // ---- O += P V (8 MFMA) ----
#pragma unroll
        for (int ks = 0; ks < 2; ++ks) {
            short8 ap = *(const short8*)(&Ps[wave][l16 * 64 + (((ks * 4 + quad) ^ (l16 & 7)) * 8)]);
#pragma unroll
            for (int nt = 0; nt < 4; ++nt) {
                const int dr = nt * 16 + l16;
                short8 bv = *(const short8*)(Vs + dr * 64 + (((ks * 4 + quad) ^ (dr & 7)) * 8));
                accO[nt] = __builtin_amdgcn_mfma_f32_16x16x32_bf16(ap, bv, accO[nt], 0, 0, 0);
            }
        }
    }

    // ---- epilogue: normalize, store bf16 to (B,T,E) ----
    float inv[4];
#pragma unroll
    for (int r = 0; r < 4; ++r) inv[r] = 1.0f / l[r];
#pragma unroll
    for (int nt = 0; nt < 4; ++nt) {
#pragma unroll
        for (int r = 0; r < 4; ++r) {
            const int t = q_row0 + r;
            o[(size_t)(b * T_SEQ + t) * E_DIM + h * 64 + nt * 16 + l16] =
                f2bf(accO[nt][r] * inv[r]);
        }
    }
}

// ---------------------------------------------------------------------------
extern "C" void kernel_launch(void* const* d_in, const int* in_sizes, int n_in,
                              void* d_out, int out_size, void* d_ws, size_t ws_size,
                              hipStream_t stream) {
    const float* x          = (const float*)d_in[0];
    const float* in_proj_w  = (const float*)d_in[1];
    const float* out_proj_w = (const float*)d_in[2];
    const float* ln1_g      = (const float*)d_in[3];
    const float* ln1_b      = (const float*)d_in[4];
    const float* ln2_g      = (const float*)d_in[5];
    const float* ln2_b      = (const float*)d_in[6];
    const float* w1         = (const float*)d_in[7];
    const float* w2         = (const float*)d_in[8];
    const int*   ctx        = (const int*)d_in[9];
    float* out = (float*)d_out;
    float* ws  = (float*)d_ws;

    // Workspace layout (byte offsets); split-K partials (bytes 0..32M) overlay
    // regions that are ALL dead during the MLP2 GEMM:
    //   0.. 6M  wqkv_b | 6..8M wout_b | 8..16M w1_b | 16..24M h_b
    //  24..32M  obuf_b | 32..56M proj_b | 56..64M vt_b
    //  64..96M  mid_b  | 96..104M w2_b | 104..104.5M tab
    const size_t MEG = 1024u * 1024u;
    unsigned short* u = (unsigned short*)ws;
    unsigned short* wqkv_b = u;                 // bytes   0..6
    unsigned short* wout_b = u + 3 * MEG;       // bytes   6..8
    unsigned short* w1_b   = u + 4 * MEG;       // bytes   8..16
    unsigned short* h_b    = u + 8 * MEG;       // bytes  16..24
    unsigned short* obuf_b = u + 12 * MEG;      // bytes  24..32
    unsigned short* proj_b = u + 16 * MEG;      // bytes  32..56
    unsigned short* vt_b   = u + 28 * MEG;      // bytes  56..64
    unsigned short* mid_b  = u + 32 * MEG;      // bytes  64..96
    unsigned short* w2_b   = u + 48 * MEG;      // bytes  96..104
    float* tab  = ws + 26 * MEG;                // bytes 104..104.5
    float* part = ws;                           // 2 slices x 16 MB, bytes 0..32

    // 0+1. fused: weights->bf16, rope table, h1 = LN1(x)
    prep_kernel<<<16640, 256, 0, stream>>>(in_proj_w, out_proj_w, w1, w2,
                                           x, ln1_g, ln1_b,
                                           wqkv_b, wout_b, w1_b, w2_b, h_b, tab);
    // 2. proj = h1 @ in_proj_w^T -> bf16   (128², 768 blocks, XCD-slab raster)
    gemm128p_bf16<4><<<dim3(3 * E_DIM / 128, M_ROWS / 128), 256, 0, stream>>>(
        h_b, wqkv_b, nullptr, proj_b, M_ROWS, 3 * E_DIM, E_DIM);
    // 3. V^T
    vtrans_kernel<<<dim3(T_SEQ / 64, B_BATCH * H_HEADS), 256, 0, stream>>>(proj_b, vt_b);
    // 4. flash attention (fused RoPE) -> obuf bf16 (B,T,E)
    attn_kernel<<<dim3(T_SEQ / 64, B_BATCH * H_HEADS), 256, 0, stream>>>(
        proj_b, vt_b, tab, ctx, obuf_b);
    // 5. out = x + obuf @ out_proj_w^T (fused residual store; m97 128² kernel)
    gemm_bf16<1><<<dim3(E_DIM / 128, M_ROWS / 128), 256, 0, stream>>>(
        obuf_b, wout_b, x, out, nullptr, M_ROWS, E_DIM, E_DIM);
    // 6. h2 = LN2(out) -> bf16
    ln_kernel<<<M_ROWS, 256, 0, stream>>>(out, ln2_g, ln2_b, h_b);
    // 7. mid = gelu(h2 @ w1^T) -> bf16   (128², 1024 blocks)
    gemm128p_bf16<2><<<dim3(F_DIM / 128, M_ROWS / 128), 256, 0, stream>>>(
        h_b, w1_b, nullptr, mid_b, M_ROWS, F_DIM, E_DIM);
    // 8. part[z] = mid @ w2^T (split-K=2, Kc=2048, 512 blocks), out += Σ part
    gemm128p_bf16<5><<<dim3(E_DIM / 128, M_ROWS / 128, 2), 256, 0, stream>>>(
        mid_b, w2_b, part, nullptr, M_ROWS, E_DIM, F_DIM);
    reduce2_kernel<<<M_ROWS * E_DIM / 1024, 256, 0, stream>>>(
        part, out, M_ROWS * E_DIM);
}